// Round 12
// baseline (614.700 us; speedup 1.0000x reference)
//
#include <hip/hip_runtime.h>

// Problem: B=4, Tq=2048, Tk=4096, E=1024, D=128, M=16384, top_k=32
// All inputs/outputs are float32 (reference is pure jnp.float32).
// NOTE: qex bits are load-bearing for the top-k boundary (round-4 post-mortem).
// Round 8: k_qkv3 4-wave LDS 2-phase pipeline. Round 9/11: k_pv LDS pipeline +
// d-split. Round 15: chunk-max sidecar (k_topk threshold from k_scores epilogue
// maxes; candidates ⊇ top-64 keys ⊇ true top-32) — WIN, 746->611.
// Round 16: k_pv K-split x2 (grid y = d-block x k-half, 2048 blocks -> 8
// blocks/CU; was 4 with fully-exposed per-step HBM latency at occupancy 16%).
// Partial sums land in osdpa0/osdpa1; k_mix adds them (one extra fp32 assoc,
// ~1e-7 relative on osdpa, no discrete boundary involved).

using bf16x8 = __attribute__((ext_vector_type(8))) short;
using f32x4  = __attribute__((ext_vector_type(4))) float;

typedef __attribute__((address_space(1))) const void GVoid;
typedef __attribute__((address_space(3))) void LVoid;
__device__ __forceinline__ void gl16(const ushort* g, ushort* l) {
  __builtin_amdgcn_global_load_lds((GVoid*)g, (LVoid*)l, 16, 0, 0);
}

__device__ __forceinline__ float bf2f(ushort h) {
  union { uint u; float f; } x; x.u = ((uint)h) << 16; return x.f;
}
__device__ __forceinline__ ushort f2bf(float f) {
  union { float f; uint u; } x; x.f = f;
  uint u = x.u;
  u += 0x7fffu + ((u >> 16) & 1u);   // RNE (finite inputs only)
  return (ushort)(u >> 16);
}
// two bf16 halves (packed in a uint) -> order-preserving uint16 keys.
__device__ __forceinline__ uint ord2(uint v) {
  uint s = (v >> 15) & 0x00010001u;   // per-half sign bit
  uint t = (s << 15) - s;             // 0x7FFF where sign, else 0
  return v ^ t ^ 0x80008000u;
}
// single bf16 -> order-preserving u16 key (same map as ord2 halves)
__device__ __forceinline__ ushort ord1(ushort h) {
  uint s = (h >> 15) & 1u;
  return (ushort)(h ^ ((s << 15) - s) ^ 0x8000u);
}

// ---- Wth[z][n][k] = bf16(W_z[k][n]) for z=0..2; Wtlq[n][k] = lo(Wq[k][n]) ----
__global__ __launch_bounds__(256) void k_wt(const float* __restrict__ Wq,
                                            const float* __restrict__ Wk,
                                            const float* __restrict__ Wv,
                                            ushort* __restrict__ Wth,
                                            ushort* __restrict__ Wtlq) {
  int id = blockIdx.x * 256 + threadIdx.x;        // 4*131072 = 524288 exact
  int z = id >> 17, r = id & 131071;
  int n = r >> 10, k = r & 1023;
  const float* W = (z == 1) ? Wk : (z == 2) ? Wv : Wq;
  float w = W[k * 128 + n];
  ushort h = f2bf(w);
  if (z < 3) Wth[id] = h;
  else       Wtlq[r] = f2bf(w - bf2f(h));
}

// ---- fp32 -> bf16 bulk convert (8 elems/thread) ----
__global__ __launch_bounds__(256) void k_cvt8(const float* __restrict__ src,
                                              ushort* __restrict__ dst) {
  int id = blockIdx.x * 256 + threadIdx.x;
  size_t base = (size_t)id * 8;
  float4 a = *(const float4*)(src + base);
  float4 b = *(const float4*)(src + base + 4);
  bf16x8 r;
  r[0] = (short)f2bf(a.x); r[1] = (short)f2bf(a.y);
  r[2] = (short)f2bf(a.z); r[3] = (short)f2bf(a.w);
  r[4] = (short)f2bf(b.x); r[5] = (short)f2bf(b.y);
  r[6] = (short)f2bf(b.z); r[7] = (short)f2bf(b.w);
  *(bf16x8*)(dst + base) = r;
}

// ---- x -> xh (hi bf16), xl (lo bf16); bit-identical to round-3 ----
__global__ __launch_bounds__(256) void k_xsplit(const float* __restrict__ x,
                                                ushort* __restrict__ xh,
                                                ushort* __restrict__ xl) {
  int id = blockIdx.x * 256 + threadIdx.x;       // 4096*256 threads, 8 elems each
  size_t base = (size_t)id * 8;
  float4 a = *(const float4*)(x + base);
  float4 b = *(const float4*)(x + base + 4);
  float xf[8] = {a.x, a.y, a.z, a.w, b.x, b.y, b.z, b.w};
  bf16x8 rh, rl;
#pragma unroll
  for (int j = 0; j < 8; ++j) {
    ushort h = f2bf(xf[j]);
    rh[j] = (short)h;
    rl[j] = (short)f2bf(xf[j] - bf2f(h));
  }
  *(bf16x8*)(xh + base) = rh;
  *(bf16x8*)(xl + base) = rl;
}

// ---- prefix: k_full/v_full[b][t<2048][d] = bf16(ki/vi[b][t][idx*128+d]) ----
__global__ __launch_bounds__(256) void k_prefix(const float* __restrict__ ki,
                                                const float* __restrict__ vi,
                                                const int* __restrict__ idx,
                                                ushort* __restrict__ kfull,
                                                ushort* __restrict__ vfull) {
  int s = idx[0] * 128;
  int id = blockIdx.x * 256 + threadIdx.x;        // 131072 chunks of 8
  int d8 = (id & 15) * 8;
  int bt = id >> 4;                                // b*2048+t
  int b = bt >> 11, t = bt & 2047;
  const float* kp = ki + (size_t)bt * 1024 + s + d8;
  const float* vp = vi + (size_t)bt * 1024 + s + d8;
  bf16x8 rk, rv;
#pragma unroll
  for (int j = 0; j < 8; ++j) { rk[j] = (short)f2bf(kp[j]); rv[j] = (short)f2bf(vp[j]); }
  size_t dst = ((size_t)b * 4096 + t) * 128 + d8;
  *(bf16x8*)(kfull + dst) = rk;
  *(bf16x8*)(vfull + dst) = rv;
}

// ---- QKV projection, 4-wave LDS 2-phase pipeline (round 8, bit-identical) ----
__global__ __launch_bounds__(256) void k_qkv3(const ushort* __restrict__ xh,
                                              const ushort* __restrict__ xl,
                                              const ushort* __restrict__ Wth,
                                              const ushort* __restrict__ Wtlq,
                                              const float* __restrict__ bq,
                                              const float* __restrict__ bk,
                                              const float* __restrict__ bv,
                                              float* __restrict__ qex,
                                              ushort* __restrict__ kfull,
                                              ushort* __restrict__ vfull) {
  __shared__ ushort lds[2][16384];   // [buf][xh 4096 | xl 4096 | Wh 4096 | Wl 4096]
  int z = blockIdx.z;
  int g = blockIdx.y;                 // column half: n in [g*64, g*64+64)
  int m0 = blockIdx.x * 64;           // 128 tiles of 64 rows
  int tid = threadIdx.x;
  int w = tid >> 6, lane = tid & 63;
  int l15 = lane & 15, q8 = (lane >> 4) * 8;
  const ushort* Wz = Wth + (size_t)z * 131072;
  const ushort* xh_src = xh + (size_t)(m0 + w * 16 + l15) * 1024 + q8;
  const ushort* xl_src = xl + (size_t)(m0 + w * 16 + l15) * 1024 + q8;
  const ushort* wh_src = Wz   + (size_t)(g * 64 + w * 16 + l15) * 1024 + q8;
  const ushort* wl_src = Wtlq + (size_t)(g * 64 + w * 16 + l15) * 1024 + q8;
  int sb = w * 1024;

  f32x4 zero = {0.f, 0.f, 0.f, 0.f};
  f32x4 acc[4] = {zero, zero, zero, zero};

  {
    ushort* B = &lds[0][0];
    gl16(xh_src,      B + sb);
    gl16(xh_src + 32, B + sb + 512);
    gl16(wh_src,      B + 8192 + sb);
    gl16(wh_src + 32, B + 8192 + sb + 512);
    if (z == 0) {
      gl16(xl_src,      B + 4096 + sb);
      gl16(xl_src + 32, B + 4096 + sb + 512);
      gl16(wl_src,      B + 12288 + sb);
      gl16(wl_src + 32, B + 12288 + sb + 512);
    }
  }
  __syncthreads();
  int bf = 0;
  for (int t16 = 0; t16 < 16; ++t16) {
    if (t16 < 15) {
      int k0 = t16 * 64 + 64;
      ushort* B = &lds[bf ^ 1][0];
      gl16(xh_src + k0,      B + sb);
      gl16(xh_src + k0 + 32, B + sb + 512);
      gl16(wh_src + k0,      B + 8192 + sb);
      gl16(wh_src + k0 + 32, B + 8192 + sb + 512);
      if (z == 0) {
        gl16(xl_src + k0,      B + 4096 + sb);
        gl16(xl_src + k0 + 32, B + 4096 + sb + 512);
        gl16(wl_src + k0,      B + 12288 + sb);
        gl16(wl_src + k0 + 32, B + 12288 + sb + 512);
      }
    }
    const ushort* B = &lds[bf][0];
    int lo = lane * 8;
    if (z == 0) {
#pragma unroll
      for (int kc = 0; kc < 2; ++kc) {
        bf16x8 ah = *(const bf16x8*)(B + (w * 2 + kc) * 512 + lo);
        bf16x8 al = *(const bf16x8*)(B + 4096 + (w * 2 + kc) * 512 + lo);
#pragma unroll
        for (int cc = 0; cc < 4; ++cc) {
          bf16x8 bh = *(const bf16x8*)(B + 8192 + (cc * 2 + kc) * 512 + lo);
          bf16x8 bl = *(const bf16x8*)(B + 12288 + (cc * 2 + kc) * 512 + lo);
          acc[cc] = __builtin_amdgcn_mfma_f32_16x16x32_bf16(ah, bh, acc[cc], 0, 0, 0);
          acc[cc] = __builtin_amdgcn_mfma_f32_16x16x32_bf16(ah, bl, acc[cc], 0, 0, 0);
          acc[cc] = __builtin_amdgcn_mfma_f32_16x16x32_bf16(al, bh, acc[cc], 0, 0, 0);
        }
      }
    } else {
#pragma unroll
      for (int kc = 0; kc < 2; ++kc) {
        bf16x8 ah = *(const bf16x8*)(B + (w * 2 + kc) * 512 + lo);
#pragma unroll
        for (int cc = 0; cc < 4; ++cc) {
          bf16x8 bh = *(const bf16x8*)(B + 8192 + (cc * 2 + kc) * 512 + lo);
          acc[cc] = __builtin_amdgcn_mfma_f32_16x16x32_bf16(ah, bh, acc[cc], 0, 0, 0);
        }
      }
    }
    __syncthreads();
    bf ^= 1;
  }

  const float* bias = (z == 0) ? bq : (z == 1) ? bk : bv;
  int mrow = m0 + w * 16 + (lane >> 4) * 4;
#pragma unroll
  for (int cc = 0; cc < 4; ++cc) {
    int n = g * 64 + cc * 16 + l15;
    float bb = bias[n];
#pragma unroll
    for (int r = 0; r < 4; ++r) {
      int m = mrow + r;
      float val = acc[cc][r] + bb;
      if (z == 0) {
        qex[(size_t)m * 128 + n] = val;
      } else {
        int b2 = m >> 11, tt = m & 2047;
        size_t o = ((size_t)b2 * 4096 + 2048 + tt) * 128 + n;
        if (z == 1) kfull[o] = f2bf(val); else vfull[o] = f2bf(val);
      }
    }
  }
}

// ---- Vt[b][d][t] = v_full[b][t][d]  (tiled transpose, bf16) ----
__global__ __launch_bounds__(256) void k_vt(const ushort* __restrict__ vfull,
                                            ushort* __restrict__ Vt) {
  __shared__ ushort lds[64][136];
  int blk = blockIdx.x;                 // 4*64 = 256
  int b = blk >> 6, t0 = (blk & 63) * 64;
  int t = threadIdx.x;
#pragma unroll
  for (int p = 0; p < 4; ++p) {
    int ch = p * 256 + t;               // 1024 chunks of 8 elems
    int row = ch >> 4, c8 = (ch & 15) * 8;
    uint4 v = *(const uint4*)(vfull + ((size_t)b * 4096 + t0 + row) * 128 + c8);
    *(uint4*)(&lds[row][c8]) = v;
  }
  __syncthreads();
#pragma unroll
  for (int p = 0; p < 8; ++p) {
    int q = p * 256 + t;                // 2048 chunks of 4 elems
    int d = q >> 4, t4 = (q & 15) * 4;
    ushort4 o;
    o.x = lds[t4 + 0][d]; o.y = lds[t4 + 1][d];
    o.z = lds[t4 + 2][d]; o.w = lds[t4 + 3][d];
    *(ushort4*)(Vt + ((size_t)b * 128 + d) * 4096 + t0 + t4) = o;
  }
}

// ---- scores GEMM: S[q][n] = bf16(A_f32[q][:]) . Bm_bf16[n][:]  (A.B^T) ----
// cmax sidecar (round 15): per row, per 64-col tile, ord-u16 of the bf16 chunk
// max (from acc regs). f2bf/ord1 monotone -> max-then-convert == max of keys.
__global__ __launch_bounds__(256) void k_scores(const float* __restrict__ A,
                                                const ushort* __restrict__ Bm,
                                                ushort* __restrict__ S,
                                                ushort* __restrict__ cmax,
                                                int N, int nslice, int causalOff,
                                                long sA, long sB, long sS) {
  __shared__ ushort Bt[64 * 136];
  int q0 = blockIdx.x * 64;
  int ns0 = blockIdx.y * nslice;
  int nend = ns0 + nslice; if (nend > N) nend = N;
  int climit = q0 + 64 + causalOff; if (nend > climit) nend = climit;
  if (ns0 >= nend) return;
  int zb = blockIdx.z;
  const float*  Ab = A  + (size_t)zb * sA;
  const ushort* Bb = Bm + (size_t)zb * sB;
  ushort* Sb = S + (size_t)zb * sS;
  int t = threadIdx.x, lane = t & 63, wv = t >> 6;
  int l15 = lane & 15, q8 = (lane >> 4) * 8;
  const float* Arow = Ab + (size_t)(q0 + wv * 16 + l15) * 128 + q8;
  bf16x8 af[4];
#pragma unroll
  for (int kc = 0; kc < 4; ++kc)
#pragma unroll
    for (int j = 0; j < 8; ++j) af[kc][j] = (short)f2bf(Arow[kc * 32 + j]);
  for (int n0 = ns0; n0 < nend; n0 += 64) {
#pragma unroll
    for (int p = 0; p < 4; ++p) {
      int ch = p * 256 + t;
      int row = ch >> 4, c8 = (ch & 15) * 8;
      uint4 v = *(const uint4*)(Bb + (size_t)(n0 + row) * 128 + c8);
      *(uint4*)(&Bt[row * 136 + c8]) = v;
    }
    __syncthreads();
    f32x4 zero = {0.f, 0.f, 0.f, 0.f};
    f32x4 acc[4] = {zero, zero, zero, zero};
#pragma unroll
    for (int h = 0; h < 4; ++h) {
#pragma unroll
      for (int kc = 0; kc < 4; ++kc) {
        bf16x8 bfr = *(const bf16x8*)(&Bt[(h * 16 + l15) * 136 + kc * 32 + q8]);
        acc[h] = __builtin_amdgcn_mfma_f32_16x16x32_bf16(af[kc], bfr, acc[h], 0, 0, 0);
      }
    }
    int qq = q0 + wv * 16 + (lane >> 4) * 4;
#pragma unroll
    for (int h = 0; h < 4; ++h)
#pragma unroll
      for (int r = 0; r < 4; ++r)
        Sb[(size_t)(qq + r) * N + (n0 + h * 16 + l15)] = f2bf(acc[h][r]);
    if (cmax) {
#pragma unroll
      for (int r = 0; r < 4; ++r) {
        float m = fmaxf(fmaxf(acc[0][r], acc[1][r]), fmaxf(acc[2][r], acc[3][r]));
#pragma unroll
        for (int off = 1; off < 16; off <<= 1) m = fmaxf(m, __shfl_xor(m, off));
        if (l15 == 0)
          cmax[(size_t)(qq + r) * 256 + (n0 >> 6)] = ord1(f2bf(m));
      }
    }
    __syncthreads();
  }
}

// ---- windowed softmax in place: P = softmax(S/sqrt(128)), zeros beyond window ----
__global__ __launch_bounds__(256) void k_softmax(ushort* __restrict__ S) {
  int rid = blockIdx.x;                // 0..8191 (b*2048+i)
  int i = rid & 2047;
  ushort* row = S + (size_t)rid * 4096;
  int w = i + 2049;                    // keys j <= i + 2048
  int t = threadIdx.x;
  const float scale = 0.08838834764831845f;  // 1/sqrt(128)
  float v[16];
  float mx = -1e30f;
#pragma unroll
  for (int c = 0; c < 16; ++c) {
    int e = c * 256 + t;
    float f = -1e30f;
    if (e < w) f = bf2f(row[e]) * scale;
    v[c] = f;
    mx = fmaxf(mx, f);
  }
  __shared__ float red[4];
#pragma unroll
  for (int off = 32; off; off >>= 1) mx = fmaxf(mx, __shfl_xor(mx, off));
  if ((t & 63) == 0) red[t >> 6] = mx;
  __syncthreads();
  mx = fmaxf(fmaxf(red[0], red[1]), fmaxf(red[2], red[3]));
  __syncthreads();
  float ex[16];
  float sum = 0.f;
#pragma unroll
  for (int c = 0; c < 16; ++c) {
    int e = c * 256 + t;
    ex[c] = (e < w) ? __expf(v[c] - mx) : 0.f;
    sum += ex[c];
  }
#pragma unroll
  for (int off = 32; off; off >>= 1) sum += __shfl_xor(sum, off);
  if ((t & 63) == 0) red[t >> 6] = sum;
  __syncthreads();
  sum = red[0] + red[1] + red[2] + red[3];
  float inv = 1.f / sum;
#pragma unroll
  for (int c = 0; c < 16; ++c) {
    int e = c * 256 + t;
    row[e] = f2bf(ex[c] * inv);        // exact zeros beyond window
  }
}

// ---- PV: 32q x 32d x k-half per block, 2 waves, LDS 2-phase pipeline ----
// Round 16: blockIdx.y = (k-half << 2) | d-block. Each block accumulates its
// k-half into O0/O1 partials; k_mix sums them. P beyond the causal window is
// exact 0 (softmax zeroes the full row) -> 64-rounding stays an exact no-op.
__global__ __launch_bounds__(128) void k_pv(const ushort* __restrict__ P,
                                            const ushort* __restrict__ Vt,
                                            float* __restrict__ O0,
                                            float* __restrict__ O1) {
  __shared__ ushort lds[2][4096];      // [buf][P 2048 | V 2048] ushorts (16 KB)
  int b = blockIdx.z;
  int kh = blockIdx.y >> 2;
  int d0 = (blockIdx.y & 3) * 32;
  int q0 = blockIdx.x * 32;
  int t = threadIdx.x, lane = t & 63, w = t >> 6;
  int l15 = lane & 15, q8 = (lane >> 4) * 8;
  int kbeg = kh * 2048;
  const ushort* Pq = P + ((size_t)b * 2048 + q0) * 4096 + kbeg;
  const ushort* Vb = Vt + (size_t)b * 128 * 4096 + kbeg;
  const ushort* p_src = Pq + (size_t)(w * 16 + l15) * 4096 + q8;
  const ushort* v_src = Vb + (size_t)(d0 + w * 16 + l15) * 4096 + q8;
  int kend = q0 + 32 + 2048; if (kend > 4096) kend = 4096;
  int klim = kend - kbeg; if (klim > 2048) klim = 2048;   // within this half
  int ksteps = (klim + 63) >> 6;                          // kh=0: always 32

  f32x4 zero = {0.f, 0.f, 0.f, 0.f};
  f32x4 acc[2] = {zero, zero};

  {
    ushort* B = &lds[0][0];
    gl16(p_src,      B + (w * 2 + 0) * 512);
    gl16(p_src + 32, B + (w * 2 + 1) * 512);
    gl16(v_src,      B + 2048 + (w * 2 + 0) * 512);
    gl16(v_src + 32, B + 2048 + (w * 2 + 1) * 512);
  }
  __syncthreads();
  int bf = 0;
  for (int st = 0; st < ksteps; ++st) {
    if (st + 1 < ksteps) {
      int k0 = st * 64 + 64;
      ushort* B = &lds[bf ^ 1][0];
      gl16(p_src + k0,      B + (w * 2 + 0) * 512);
      gl16(p_src + k0 + 32, B + (w * 2 + 1) * 512);
      gl16(v_src + k0,      B + 2048 + (w * 2 + 0) * 512);
      gl16(v_src + k0 + 32, B + 2048 + (w * 2 + 1) * 512);
    }
    const ushort* B = &lds[bf][0];
    int lo = lane * 8;
#pragma unroll
    for (int kc = 0; kc < 2; ++kc) {
      bf16x8 af = *(const bf16x8*)(B + (w * 2 + kc) * 512 + lo);
#pragma unroll
      for (int nc = 0; nc < 2; ++nc) {
        bf16x8 bfr = *(const bf16x8*)(B + 2048 + (nc * 2 + kc) * 512 + lo);
        acc[nc] = __builtin_amdgcn_mfma_f32_16x16x32_bf16(af, bfr, acc[nc], 0, 0, 0);
      }
    }
    __syncthreads();
    bf ^= 1;
  }

  float* O = kh ? O1 : O0;
  size_t ob = ((size_t)b * 2048 + q0 + w * 16 + (lane >> 4) * 4) * 128;
#pragma unroll
  for (int nc = 0; nc < 2; ++nc)
#pragma unroll
    for (int r = 0; r < 4; ++r)
      O[ob + (size_t)r * 128 + d0 + nc * 16 + l15] = acc[nc][r];
}

// ---- exact top-32 kNN attention, chunk-max assisted (round 15) ----
__global__ __launch_bounds__(256) void k_topk(const ushort* __restrict__ Sall,
                                              const ushort* __restrict__ cmaxA,
                                              const float* __restrict__ qf32b,
                                              const float* __restrict__ memk,
                                              const float* __restrict__ memv,
                                              float* __restrict__ mout) {
  __shared__ ushort marr[256];
  __shared__ ushort chun[256];
  __shared__ float qf[128];
  __shared__ uint cidx[384];
  __shared__ float csc[384];
  __shared__ unsigned long long ckey[384];
  __shared__ uint selIdx[32];
  __shared__ float selS[32];
  __shared__ float obuf[256];
  __shared__ int nF, nC;
  __shared__ uint sT;

  int i = blockIdx.x;
  const ushort* Srow = Sall + (size_t)i * 16384;
  int t = threadIdx.x;
  int wv = t >> 6, lane = t & 63;
  if (t < 128) qf[t] = qf32b[(size_t)i * 128 + t];
  if (t == 0) { nF = 0; nC = 0; }
  uint cm = cmaxA[(size_t)i * 256 + t];
  marr[t] = (ushort)cm;
  __syncthreads();

  // T' = chunk max with rank 63 (value desc, index asc)
  {
    int rank = 0;
#pragma unroll 8
    for (int j = 0; j < 256; ++j) {
      uint vj = marr[j];
      rank += (vj > cm) || (vj == cm && j < t);
    }
    if (rank == 63) sT = cm;
  }
  __syncthreads();
  uint T = sT;
  if (cm >= T) { int p = atomicAdd(&nF, 1); chun[p] = (ushort)t; }
  __syncthreads();
  int F = nF;

  // scan flagged chunks: 8 threads per chunk, 8 keys per thread
  for (int jj = (t >> 3); jj < F; jj += 32) {
    int base = ((int)chun[jj]) * 64 + (t & 7) * 8;
    uint4 rv = *(const uint4*)(Srow + base);
    uint a0 = ord2(rv.x), a1 = ord2(rv.y), a2 = ord2(rv.z), a3 = ord2(rv.w);
    if ((a0 & 0xffffu) >= T) { int p = atomicAdd(&nC, 1); if (p < 384) cidx[p] = (uint)(base + 0); }
    if ((a0 >> 16)     >= T) { int p = atomicAdd(&nC, 1); if (p < 384) cidx[p] = (uint)(base + 1); }
    if ((a1 & 0xffffu) >= T) { int p = atomicAdd(&nC, 1); if (p < 384) cidx[p] = (uint)(base + 2); }
    if ((a1 >> 16)     >= T) { int p = atomicAdd(&nC, 1); if (p < 384) cidx[p] = (uint)(base + 3); }
    if ((a2 & 0xffffu) >= T) { int p = atomicAdd(&nC, 1); if (p < 384) cidx[p] = (uint)(base + 4); }
    if ((a2 >> 16)     >= T) { int p = atomicAdd(&nC, 1); if (p < 384) cidx[p] = (uint)(base + 5); }
    if ((a3 & 0xffffu) >= T) { int p = atomicAdd(&nC, 1); if (p < 384) cidx[p] = (uint)(base + 6); }
    if ((a3 >> 16)     >= T) { int p = atomicAdd(&nC, 1); if (p < 384) cidx[p] = (uint)(base + 7); }
  }
  __syncthreads();
  int C = nC; if (C > 384) C = 384;

  // refine: exact fp32 scores, 8 candidates in flight per wave (round-7)
  {
    float qa = qf[lane * 2], qb = qf[lane * 2 + 1];
    for (int j0 = wv; j0 < C; j0 += 32) {
      float2 pp[8];
      float s[8];
#pragma unroll
      for (int u = 0; u < 8; ++u) {
        int j = j0 + u * 4;
        if (j < C) pp[u] = *(const float2*)(memk + (size_t)cidx[j] * 128 + lane * 2);
      }
#pragma unroll
      for (int u = 0; u < 8; ++u) {
        int j = j0 + u * 4;
        s[u] = (j < C) ? (qa * pp[u].x + qb * pp[u].y) : 0.f;
      }
#pragma unroll
      for (int off = 32; off; off >>= 1) {
#pragma unroll
        for (int u = 0; u < 8; ++u) s[u] += __shfl_xor(s[u], off);
      }
      if (lane == 0) {
#pragma unroll
        for (int u = 0; u < 8; ++u) {
          int j = j0 + u * 4;
          if (j < C) csc[j] = s[u];
        }
      }
    }
  }
  __syncthreads();
  // rank-by-counting top-32 (comparator: score desc, index asc)
  for (int j = t; j < C; j += 256) {
    uint sb2 = __float_as_uint(csc[j]);
    uint o = (sb2 & 0x80000000u) ? ~sb2 : (sb2 | 0x80000000u);
    ckey[j] = ((unsigned long long)o << 32) | (uint)(~cidx[j]);
  }
  __syncthreads();
  for (int j = t; j < C; j += 256) {
    unsigned long long my = ckey[j];
    int rank = 0;
    for (int l = 0; l < C; ++l) rank += (ckey[l] > my) ? 1 : 0;
    if (rank < 32) { selS[rank] = csc[j]; selIdx[rank] = cidx[j]; }
  }
  __syncthreads();
  // softmax over the 32 (wave 0, identical math)
  if (wv == 0) {
    float sc = (lane < 32) ? selS[lane] * 0.03125f : -1e30f;  // 1/sqrt(1024)
    float mx = sc;
#pragma unroll
    for (int off = 32; off; off >>= 1) mx = fmaxf(mx, __shfl_xor(mx, off));
    float ex = (lane < 32) ? __expf(sc - mx) : 0.f;
    float Z = ex;
#pragma unroll
    for (int off = 32; off; off >>= 1) Z += __shfl_xor(Z, off);
    if (lane < 32) selS[lane] = ex / Z;
  }
  __syncthreads();
  // gather: 256 threads, two j-halves per output element; loads hoisted
  {
    int d = t & 127, half = t >> 7;
    float vv[16];
#pragma unroll
    for (int u = 0; u < 16; ++u)
      vv[u] = memv[(size_t)selIdx[half * 16 + u] * 128 + d];
    float acc = 0.f;
#pragma unroll
    for (int u = 0; u < 16; ++u)
      acc += selS[half * 16 + u] * vv[u];
    obuf[t] = acc;
  }
  __syncthreads();
  if (t < 128) mout[(size_t)i * 128 + t] = obuf[t] + obuf[t + 128];
}

// ---- final gate mix (fp32 out): out = (a0+a1)*g + b*(1-g) ----
__global__ __launch_bounds__(256) void k_mix(const float* __restrict__ a0,
                                             const float* __restrict__ a1,
                                             const float* __restrict__ b,
                                             const float* __restrict__ gate,
                                             float* __restrict__ out) {
  int id = blockIdx.x * 256 + threadIdx.x;   // 262144 chunks of 4
  float g = gate[0];
  float4 v0 = ((const float4*)a0)[id];
  float4 v1 = ((const float4*)a1)[id];
  float4 vb = ((const float4*)b)[id];
  float4 o;
  o.x = (v0.x + v1.x) * g + vb.x * (1.f - g);
  o.y = (v0.y + v1.y) * g + vb.y * (1.f - g);
  o.z = (v0.z + v1.z) * g + vb.z * (1.f - g);
  o.w = (v0.w + v1.w) * g + vb.w * (1.f - g);
  ((float4*)out)[id] = o;
}

extern "C" void kernel_launch(void* const* d_in, const int* in_sizes, int n_in,
                              void* d_out, int out_size, void* d_ws, size_t ws_size,
                              hipStream_t stream) {
  const float* x    = (const float*)d_in[0];
  const float* ki   = (const float*)d_in[1];
  const float* vi   = (const float*)d_in[2];
  const float* mk   = (const float*)d_in[3];
  const float* mv   = (const float*)d_in[4];
  const float* Wq   = (const float*)d_in[5];
  const float* bq   = (const float*)d_in[6];
  const float* Wk   = (const float*)d_in[7];
  const float* bk   = (const float*)d_in[8];
  const float* Wv   = (const float*)d_in[9];
  const float* bv   = (const float*)d_in[10];
  const float* gate = (const float*)d_in[11];
  const int*   idx  = (const int*)d_in[12];

  char* ws = (char*)d_ws;
  ushort* Sbuf  = (ushort*)(ws);                 // 64 MiB scores (SDPA, then per-batch mem)
  ushort* xh    = (ushort*)(ws);                 // 16 MiB bf16 x hi (pre-SDPA only, inside Sbuf)
  ushort* xl    = (ushort*)(ws + 16777216);      // 16 MiB bf16 x lo (pre-SDPA only)
  float*  qex   = (float*) (ws + 67108864);      // 4 MiB fp32 q (near-exact)
  ushort* kfull = (ushort*)(ws + 71303168);      // 4 MiB
  ushort* vfull = (ushort*)(ws + 75497472);      // 4 MiB
  ushort* Vt    = (ushort*)(ws + 79691776);      // 4 MiB
  ushort* mkb   = (ushort*)(ws + 83886080);      // 16 MiB bf16 mem_keys
  ushort* Wth   = (ushort*)(ws + 100663296);     // 768 KiB
  ushort* Wtlq  = (ushort*)(ws + 101449728);     // 256 KiB
  float*  osdp0 = (float*) (ws + 101711872);     // 4 MiB k-half 0
  float*  mout  = (float*) (ws + 105906176);     // 4 MiB
  ushort* cmaxb = (ushort*)(ws + 110100480);     // 1 MiB chunk-max sidecar
  float*  osdp1 = (float*) (ws + 111149056);     // 4 MiB k-half 1 (end ~110 MiB)

  k_wt<<<2048, 256, 0, stream>>>(Wq, Wk, Wv, Wth, Wtlq);
  k_cvt8<<<4096, 256, 0, stream>>>(mk, mkb);     // 4*16384*128 / 8 / 256
  k_xsplit<<<4096, 256, 0, stream>>>(x, xh, xl); // 8192*1024 / 8 / 256
  k_prefix<<<512, 256, 0, stream>>>(ki, vi, idx, kfull, vfull);

  // QKV: 4-wave LDS-pipelined blocks, 128 m-tiles x 2 col-halves x 3 z
  k_qkv3<<<dim3(128, 2, 3), 256, 0, stream>>>(xh, xl, Wth, Wtlq, bq, bk, bv,
                                              qex, kfull, vfull);
  k_vt<<<256, 256, 0, stream>>>(vfull, Vt);

  // SDPA: scores -> windowed softmax (in place) -> PV (K-split x2)
  k_scores<<<dim3(32, 8, 4), 256, 0, stream>>>(qex, kfull, Sbuf, nullptr,
                                               4096, 512, 2048,
                                               (long)2048 * 128, (long)4096 * 128,
                                               (long)2048 * 4096);
  k_softmax<<<8192, 256, 0, stream>>>(Sbuf);
  k_pv<<<dim3(64, 8, 4), 128, 0, stream>>>(Sbuf, Vt, osdp0, osdp1);

  // kNN memory attention, per batch (reuses Sbuf; cmax sidecar per batch)
  for (int b = 0; b < 4; ++b) {
    k_scores<<<dim3(32, 32, 1), 256, 0, stream>>>(qex + (size_t)b * 2048 * 128,
                                                  mkb + (size_t)b * 16384 * 128,
                                                  Sbuf, cmaxb,
                                                  16384, 512, (1 << 28),
                                                  0, 0, 0);
    k_topk<<<2048, 256, 0, stream>>>(Sbuf, cmaxb,
                                     qex + (size_t)b * 2048 * 128,
                                     mk + (size_t)b * 16384 * 128,
                                     mv + (size_t)b * 16384 * 128,
                                     mout + (size_t)b * 2048 * 128);
  }

  k_mix<<<1024, 256, 0, stream>>>(osdp0, osdp1, mout, gate, (float*)d_out);
}

// Round 13
// 605.376 us; speedup vs baseline: 1.0154x; 1.0154x over previous
//
#include <hip/hip_runtime.h>

// Problem: B=4, Tq=2048, Tk=4096, E=1024, D=128, M=16384, top_k=32
// All inputs/outputs are float32 (reference is pure jnp.float32).
// NOTE: qex bits are load-bearing for the top-k boundary (round-4 post-mortem).
// Round 8: k_qkv3 4-wave LDS 2-phase pipeline. Round 11: k_pv d-split (best
// k_pv form; round-16 K-split was TLP-invariant -> reverted). Round 15:
// chunk-max sidecar for k_topk (WIN 746->611). Round 17: k_scores rebuilt with
// gl16 swizzled staging done RIGHT (rule #21: linear LDS dest, inverse-swizzled
// SOURCE — a within-256B chunk permutation, still 4x64B coalesced — and
// swizzled READ p = c ^ (row&7), 8 lanes/bank-group = LDS floor). Bytes per
// (row,chunk) identical to the old padded layout -> S bit-identical.

using bf16x8 = __attribute__((ext_vector_type(8))) short;
using f32x4  = __attribute__((ext_vector_type(4))) float;

typedef __attribute__((address_space(1))) const void GVoid;
typedef __attribute__((address_space(3))) void LVoid;
__device__ __forceinline__ void gl16(const ushort* g, ushort* l) {
  __builtin_amdgcn_global_load_lds((GVoid*)g, (LVoid*)l, 16, 0, 0);
}

__device__ __forceinline__ float bf2f(ushort h) {
  union { uint u; float f; } x; x.u = ((uint)h) << 16; return x.f;
}
__device__ __forceinline__ ushort f2bf(float f) {
  union { float f; uint u; } x; x.f = f;
  uint u = x.u;
  u += 0x7fffu + ((u >> 16) & 1u);   // RNE (finite inputs only)
  return (ushort)(u >> 16);
}
// two bf16 halves (packed in a uint) -> order-preserving uint16 keys.
__device__ __forceinline__ uint ord2(uint v) {
  uint s = (v >> 15) & 0x00010001u;   // per-half sign bit
  uint t = (s << 15) - s;             // 0x7FFF where sign, else 0
  return v ^ t ^ 0x80008000u;
}
// single bf16 -> order-preserving u16 key (same map as ord2 halves)
__device__ __forceinline__ ushort ord1(ushort h) {
  uint s = (h >> 15) & 1u;
  return (ushort)(h ^ ((s << 15) - s) ^ 0x8000u);
}

// ---- Wth[z][n][k] = bf16(W_z[k][n]) for z=0..2; Wtlq[n][k] = lo(Wq[k][n]) ----
__global__ __launch_bounds__(256) void k_wt(const float* __restrict__ Wq,
                                            const float* __restrict__ Wk,
                                            const float* __restrict__ Wv,
                                            ushort* __restrict__ Wth,
                                            ushort* __restrict__ Wtlq) {
  int id = blockIdx.x * 256 + threadIdx.x;        // 4*131072 = 524288 exact
  int z = id >> 17, r = id & 131071;
  int n = r >> 10, k = r & 1023;
  const float* W = (z == 1) ? Wk : (z == 2) ? Wv : Wq;
  float w = W[k * 128 + n];
  ushort h = f2bf(w);
  if (z < 3) Wth[id] = h;
  else       Wtlq[r] = f2bf(w - bf2f(h));
}

// ---- fp32 -> bf16 bulk convert (8 elems/thread) ----
__global__ __launch_bounds__(256) void k_cvt8(const float* __restrict__ src,
                                              ushort* __restrict__ dst) {
  int id = blockIdx.x * 256 + threadIdx.x;
  size_t base = (size_t)id * 8;
  float4 a = *(const float4*)(src + base);
  float4 b = *(const float4*)(src + base + 4);
  bf16x8 r;
  r[0] = (short)f2bf(a.x); r[1] = (short)f2bf(a.y);
  r[2] = (short)f2bf(a.z); r[3] = (short)f2bf(a.w);
  r[4] = (short)f2bf(b.x); r[5] = (short)f2bf(b.y);
  r[6] = (short)f2bf(b.z); r[7] = (short)f2bf(b.w);
  *(bf16x8*)(dst + base) = r;
}

// ---- x -> xh (hi bf16), xl (lo bf16); bit-identical to round-3 ----
__global__ __launch_bounds__(256) void k_xsplit(const float* __restrict__ x,
                                                ushort* __restrict__ xh,
                                                ushort* __restrict__ xl) {
  int id = blockIdx.x * 256 + threadIdx.x;       // 4096*256 threads, 8 elems each
  size_t base = (size_t)id * 8;
  float4 a = *(const float4*)(x + base);
  float4 b = *(const float4*)(x + base + 4);
  float xf[8] = {a.x, a.y, a.z, a.w, b.x, b.y, b.z, b.w};
  bf16x8 rh, rl;
#pragma unroll
  for (int j = 0; j < 8; ++j) {
    ushort h = f2bf(xf[j]);
    rh[j] = (short)h;
    rl[j] = (short)f2bf(xf[j] - bf2f(h));
  }
  *(bf16x8*)(xh + base) = rh;
  *(bf16x8*)(xl + base) = rl;
}

// ---- prefix: k_full/v_full[b][t<2048][d] = bf16(ki/vi[b][t][idx*128+d]) ----
__global__ __launch_bounds__(256) void k_prefix(const float* __restrict__ ki,
                                                const float* __restrict__ vi,
                                                const int* __restrict__ idx,
                                                ushort* __restrict__ kfull,
                                                ushort* __restrict__ vfull) {
  int s = idx[0] * 128;
  int id = blockIdx.x * 256 + threadIdx.x;        // 131072 chunks of 8
  int d8 = (id & 15) * 8;
  int bt = id >> 4;                                // b*2048+t
  int b = bt >> 11, t = bt & 2047;
  const float* kp = ki + (size_t)bt * 1024 + s + d8;
  const float* vp = vi + (size_t)bt * 1024 + s + d8;
  bf16x8 rk, rv;
#pragma unroll
  for (int j = 0; j < 8; ++j) { rk[j] = (short)f2bf(kp[j]); rv[j] = (short)f2bf(vp[j]); }
  size_t dst = ((size_t)b * 4096 + t) * 128 + d8;
  *(bf16x8*)(kfull + dst) = rk;
  *(bf16x8*)(vfull + dst) = rv;
}

// ---- QKV projection, 4-wave LDS 2-phase pipeline (round 8, bit-identical) ----
__global__ __launch_bounds__(256) void k_qkv3(const ushort* __restrict__ xh,
                                              const ushort* __restrict__ xl,
                                              const ushort* __restrict__ Wth,
                                              const ushort* __restrict__ Wtlq,
                                              const float* __restrict__ bq,
                                              const float* __restrict__ bk,
                                              const float* __restrict__ bv,
                                              float* __restrict__ qex,
                                              ushort* __restrict__ kfull,
                                              ushort* __restrict__ vfull) {
  __shared__ ushort lds[2][16384];   // [buf][xh 4096 | xl 4096 | Wh 4096 | Wl 4096]
  int z = blockIdx.z;
  int g = blockIdx.y;                 // column half: n in [g*64, g*64+64)
  int m0 = blockIdx.x * 64;           // 128 tiles of 64 rows
  int tid = threadIdx.x;
  int w = tid >> 6, lane = tid & 63;
  int l15 = lane & 15, q8 = (lane >> 4) * 8;
  const ushort* Wz = Wth + (size_t)z * 131072;
  const ushort* xh_src = xh + (size_t)(m0 + w * 16 + l15) * 1024 + q8;
  const ushort* xl_src = xl + (size_t)(m0 + w * 16 + l15) * 1024 + q8;
  const ushort* wh_src = Wz   + (size_t)(g * 64 + w * 16 + l15) * 1024 + q8;
  const ushort* wl_src = Wtlq + (size_t)(g * 64 + w * 16 + l15) * 1024 + q8;
  int sb = w * 1024;

  f32x4 zero = {0.f, 0.f, 0.f, 0.f};
  f32x4 acc[4] = {zero, zero, zero, zero};

  {
    ushort* B = &lds[0][0];
    gl16(xh_src,      B + sb);
    gl16(xh_src + 32, B + sb + 512);
    gl16(wh_src,      B + 8192 + sb);
    gl16(wh_src + 32, B + 8192 + sb + 512);
    if (z == 0) {
      gl16(xl_src,      B + 4096 + sb);
      gl16(xl_src + 32, B + 4096 + sb + 512);
      gl16(wl_src,      B + 12288 + sb);
      gl16(wl_src + 32, B + 12288 + sb + 512);
    }
  }
  __syncthreads();
  int bf = 0;
  for (int t16 = 0; t16 < 16; ++t16) {
    if (t16 < 15) {
      int k0 = t16 * 64 + 64;
      ushort* B = &lds[bf ^ 1][0];
      gl16(xh_src + k0,      B + sb);
      gl16(xh_src + k0 + 32, B + sb + 512);
      gl16(wh_src + k0,      B + 8192 + sb);
      gl16(wh_src + k0 + 32, B + 8192 + sb + 512);
      if (z == 0) {
        gl16(xl_src + k0,      B + 4096 + sb);
        gl16(xl_src + k0 + 32, B + 4096 + sb + 512);
        gl16(wl_src + k0,      B + 12288 + sb);
        gl16(wl_src + k0 + 32, B + 12288 + sb + 512);
      }
    }
    const ushort* B = &lds[bf][0];
    int lo = lane * 8;
    if (z == 0) {
#pragma unroll
      for (int kc = 0; kc < 2; ++kc) {
        bf16x8 ah = *(const bf16x8*)(B + (w * 2 + kc) * 512 + lo);
        bf16x8 al = *(const bf16x8*)(B + 4096 + (w * 2 + kc) * 512 + lo);
#pragma unroll
        for (int cc = 0; cc < 4; ++cc) {
          bf16x8 bh = *(const bf16x8*)(B + 8192 + (cc * 2 + kc) * 512 + lo);
          bf16x8 bl = *(const bf16x8*)(B + 12288 + (cc * 2 + kc) * 512 + lo);
          acc[cc] = __builtin_amdgcn_mfma_f32_16x16x32_bf16(ah, bh, acc[cc], 0, 0, 0);
          acc[cc] = __builtin_amdgcn_mfma_f32_16x16x32_bf16(ah, bl, acc[cc], 0, 0, 0);
          acc[cc] = __builtin_amdgcn_mfma_f32_16x16x32_bf16(al, bh, acc[cc], 0, 0, 0);
        }
      }
    } else {
#pragma unroll
      for (int kc = 0; kc < 2; ++kc) {
        bf16x8 ah = *(const bf16x8*)(B + (w * 2 + kc) * 512 + lo);
#pragma unroll
        for (int cc = 0; cc < 4; ++cc) {
          bf16x8 bh = *(const bf16x8*)(B + 8192 + (cc * 2 + kc) * 512 + lo);
          acc[cc] = __builtin_amdgcn_mfma_f32_16x16x32_bf16(ah, bh, acc[cc], 0, 0, 0);
        }
      }
    }
    __syncthreads();
    bf ^= 1;
  }

  const float* bias = (z == 0) ? bq : (z == 1) ? bk : bv;
  int mrow = m0 + w * 16 + (lane >> 4) * 4;
#pragma unroll
  for (int cc = 0; cc < 4; ++cc) {
    int n = g * 64 + cc * 16 + l15;
    float bb = bias[n];
#pragma unroll
    for (int r = 0; r < 4; ++r) {
      int m = mrow + r;
      float val = acc[cc][r] + bb;
      if (z == 0) {
        qex[(size_t)m * 128 + n] = val;
      } else {
        int b2 = m >> 11, tt = m & 2047;
        size_t o = ((size_t)b2 * 4096 + 2048 + tt) * 128 + n;
        if (z == 1) kfull[o] = f2bf(val); else vfull[o] = f2bf(val);
      }
    }
  }
}

// ---- Vt[b][d][t] = v_full[b][t][d]  (tiled transpose, bf16) ----
__global__ __launch_bounds__(256) void k_vt(const ushort* __restrict__ vfull,
                                            ushort* __restrict__ Vt) {
  __shared__ ushort lds[64][136];
  int blk = blockIdx.x;                 // 4*64 = 256
  int b = blk >> 6, t0 = (blk & 63) * 64;
  int t = threadIdx.x;
#pragma unroll
  for (int p = 0; p < 4; ++p) {
    int ch = p * 256 + t;               // 1024 chunks of 8 elems
    int row = ch >> 4, c8 = (ch & 15) * 8;
    uint4 v = *(const uint4*)(vfull + ((size_t)b * 4096 + t0 + row) * 128 + c8);
    *(uint4*)(&lds[row][c8]) = v;
  }
  __syncthreads();
#pragma unroll
  for (int p = 0; p < 8; ++p) {
    int q = p * 256 + t;                // 2048 chunks of 4 elems
    int d = q >> 4, t4 = (q & 15) * 4;
    ushort4 o;
    o.x = lds[t4 + 0][d]; o.y = lds[t4 + 1][d];
    o.z = lds[t4 + 2][d]; o.w = lds[t4 + 3][d];
    *(ushort4*)(Vt + ((size_t)b * 128 + d) * 4096 + t0 + t4) = o;
  }
}

// ---- scores GEMM: S[q][n] = bf16(A_f32[q][:]) . Bm_bf16[n][:]  (A.B^T) ----
// Round 17: B staged via gl16 into linear [64][128] LDS, double-buffered.
// Source chunk for lane l of stage #i: row rr = wv*16+i*4+(l>>4),
// chunk c = (l&15) ^ (rr&7)  (within-256B permutation -> same 4x64B lines,
// fully coalesced). MFMA read: position p = (kc*4+u) ^ (row&7) -> 8 lanes per
// bank-group = LDS throughput floor. Bytes per (row,chunk) identical to the
// old padded layout -> S bit-identical. cmax sidecar unchanged (round 15).
__global__ __launch_bounds__(256) void k_scores(const float* __restrict__ A,
                                                const ushort* __restrict__ Bm,
                                                ushort* __restrict__ S,
                                                ushort* __restrict__ cmax,
                                                int N, int nslice, int causalOff,
                                                long sA, long sB, long sS) {
  __shared__ __align__(16) ushort Bt[2][8192];   // 2 x 16KB, [64 rows][128]
  int q0 = blockIdx.x * 64;
  int ns0 = blockIdx.y * nslice;
  int nend = ns0 + nslice; if (nend > N) nend = N;
  int climit = q0 + 64 + causalOff; if (nend > climit) nend = climit;
  if (ns0 >= nend) return;
  int zb = blockIdx.z;
  const float*  Ab = A  + (size_t)zb * sA;
  const ushort* Bb = Bm + (size_t)zb * sB;
  ushort* Sb = S + (size_t)zb * sS;
  int t = threadIdx.x, lane = t & 63, wv = t >> 6;
  int l15 = lane & 15, q8 = (lane >> 4) * 8;
  const float* Arow = Ab + (size_t)(q0 + wv * 16 + l15) * 128 + q8;
  bf16x8 af[4];
#pragma unroll
  for (int kc = 0; kc < 4; ++kc)
#pragma unroll
    for (int j = 0; j < 8; ++j) af[kc][j] = (short)f2bf(Arow[kc * 32 + j]);
  // per-lane staging geometry (stage #i handles rows wv*16+i*4 .. +3)
  int srow[4], soff[4];
#pragma unroll
  for (int i = 0; i < 4; ++i) {
    int br = wv * 16 + i * 4;
    int rr = br + (lane >> 4);
    int c  = (l15) ^ (rr & 7);
    srow[i] = rr;
    soff[i] = c * 8;
  }
  // prologue: stage first tile into buffer 0
  {
#pragma unroll
    for (int i = 0; i < 4; ++i)
      gl16(Bb + (size_t)(ns0 + srow[i]) * 128 + soff[i],
           &Bt[0][(wv * 16 + i * 4) * 128]);
  }
  __syncthreads();
  int bf = 0;
  for (int n0 = ns0; n0 < nend; n0 += 64) {
    if (n0 + 64 < nend) {              // issue next tile's async stage first
#pragma unroll
      for (int i = 0; i < 4; ++i)
        gl16(Bb + (size_t)(n0 + 64 + srow[i]) * 128 + soff[i],
             &Bt[bf ^ 1][(wv * 16 + i * 4) * 128]);
    }
    const ushort* B = &Bt[bf][0];
    f32x4 zero = {0.f, 0.f, 0.f, 0.f};
    f32x4 acc[4] = {zero, zero, zero, zero};
#pragma unroll
    for (int h = 0; h < 4; ++h) {
#pragma unroll
      for (int kc = 0; kc < 4; ++kc) {
        int row = h * 16 + l15;
        int p = (kc * 4 + (lane >> 4)) ^ (row & 7);
        bf16x8 bfr = *(const bf16x8*)(B + row * 128 + p * 8);
        acc[h] = __builtin_amdgcn_mfma_f32_16x16x32_bf16(af[kc], bfr, acc[h], 0, 0, 0);
      }
    }
    int qq = q0 + wv * 16 + (lane >> 4) * 4;
#pragma unroll
    for (int h = 0; h < 4; ++h)
#pragma unroll
      for (int r = 0; r < 4; ++r)
        Sb[(size_t)(qq + r) * N + (n0 + h * 16 + l15)] = f2bf(acc[h][r]);
    if (cmax) {
#pragma unroll
      for (int r = 0; r < 4; ++r) {
        float m = fmaxf(fmaxf(acc[0][r], acc[1][r]), fmaxf(acc[2][r], acc[3][r]));
#pragma unroll
        for (int off = 1; off < 16; off <<= 1) m = fmaxf(m, __shfl_xor(m, off));
        if (l15 == 0)
          cmax[(size_t)(qq + r) * 256 + (n0 >> 6)] = ord1(f2bf(m));
      }
    }
    __syncthreads();                   // drains stage vmcnt + protects buf reuse
    bf ^= 1;
  }
}

// ---- windowed softmax in place: P = softmax(S/sqrt(128)), zeros beyond window ----
__global__ __launch_bounds__(256) void k_softmax(ushort* __restrict__ S) {
  int rid = blockIdx.x;                // 0..8191 (b*2048+i)
  int i = rid & 2047;
  ushort* row = S + (size_t)rid * 4096;
  int w = i + 2049;                    // keys j <= i + 2048
  int t = threadIdx.x;
  const float scale = 0.08838834764831845f;  // 1/sqrt(128)
  float v[16];
  float mx = -1e30f;
#pragma unroll
  for (int c = 0; c < 16; ++c) {
    int e = c * 256 + t;
    float f = -1e30f;
    if (e < w) f = bf2f(row[e]) * scale;
    v[c] = f;
    mx = fmaxf(mx, f);
  }
  __shared__ float red[4];
#pragma unroll
  for (int off = 32; off; off >>= 1) mx = fmaxf(mx, __shfl_xor(mx, off));
  if ((t & 63) == 0) red[t >> 6] = mx;
  __syncthreads();
  mx = fmaxf(fmaxf(red[0], red[1]), fmaxf(red[2], red[3]));
  __syncthreads();
  float ex[16];
  float sum = 0.f;
#pragma unroll
  for (int c = 0; c < 16; ++c) {
    int e = c * 256 + t;
    ex[c] = (e < w) ? __expf(v[c] - mx) : 0.f;
    sum += ex[c];
  }
#pragma unroll
  for (int off = 32; off; off >>= 1) sum += __shfl_xor(sum, off);
  if ((t & 63) == 0) red[t >> 6] = sum;
  __syncthreads();
  sum = red[0] + red[1] + red[2] + red[3];
  float inv = 1.f / sum;
#pragma unroll
  for (int c = 0; c < 16; ++c) {
    int e = c * 256 + t;
    row[e] = f2bf(ex[c] * inv);        // exact zeros beyond window
  }
}

// ---- PV: 32q x 32d per block, 2 waves, LDS 2-phase pipeline (round 11) ----
__global__ __launch_bounds__(128) void k_pv(const ushort* __restrict__ P,
                                            const ushort* __restrict__ Vt,
                                            float* __restrict__ O) {
  __shared__ ushort lds[2][4096];      // [buf][P 2048 | V 2048] ushorts (16 KB)
  int b = blockIdx.z;
  int d0 = blockIdx.y * 32;
  int q0 = blockIdx.x * 32;
  int t = threadIdx.x, lane = t & 63, w = t >> 6;
  int l15 = lane & 15, q8 = (lane >> 4) * 8;
  const ushort* Pq = P + ((size_t)b * 2048 + q0) * 4096;
  const ushort* Vb = Vt + (size_t)b * 128 * 4096;
  const ushort* p_src = Pq + (size_t)(w * 16 + l15) * 4096 + q8;
  const ushort* v_src = Vb + (size_t)(d0 + w * 16 + l15) * 4096 + q8;
  int kend = q0 + 32 + 2048; if (kend > 4096) kend = 4096;
  int ksteps = (kend + 63) >> 6;

  f32x4 zero = {0.f, 0.f, 0.f, 0.f};
  f32x4 acc[2] = {zero, zero};

  {
    ushort* B = &lds[0][0];
    gl16(p_src,      B + (w * 2 + 0) * 512);
    gl16(p_src + 32, B + (w * 2 + 1) * 512);
    gl16(v_src,      B + 2048 + (w * 2 + 0) * 512);
    gl16(v_src + 32, B + 2048 + (w * 2 + 1) * 512);
  }
  __syncthreads();
  int bf = 0;
  for (int st = 0; st < ksteps; ++st) {
    if (st + 1 < ksteps) {
      int k0 = st * 64 + 64;
      ushort* B = &lds[bf ^ 1][0];
      gl16(p_src + k0,      B + (w * 2 + 0) * 512);
      gl16(p_src + k0 + 32, B + (w * 2 + 1) * 512);
      gl16(v_src + k0,      B + 2048 + (w * 2 + 0) * 512);
      gl16(v_src + k0 + 32, B + 2048 + (w * 2 + 1) * 512);
    }
    const ushort* B = &lds[bf][0];
    int lo = lane * 8;
#pragma unroll
    for (int kc = 0; kc < 2; ++kc) {
      bf16x8 af = *(const bf16x8*)(B + (w * 2 + kc) * 512 + lo);
#pragma unroll
      for (int nc = 0; nc < 2; ++nc) {
        bf16x8 bfr = *(const bf16x8*)(B + 2048 + (nc * 2 + kc) * 512 + lo);
        acc[nc] = __builtin_amdgcn_mfma_f32_16x16x32_bf16(af, bfr, acc[nc], 0, 0, 0);
      }
    }
    __syncthreads();
    bf ^= 1;
  }

  size_t ob = ((size_t)b * 2048 + q0 + w * 16 + (lane >> 4) * 4) * 128;
#pragma unroll
  for (int nc = 0; nc < 2; ++nc)
#pragma unroll
    for (int r = 0; r < 4; ++r)
      O[ob + (size_t)r * 128 + d0 + nc * 16 + l15] = acc[nc][r];
}

// ---- exact top-32 kNN attention, chunk-max assisted (round 15) ----
__global__ __launch_bounds__(256) void k_topk(const ushort* __restrict__ Sall,
                                              const ushort* __restrict__ cmaxA,
                                              const float* __restrict__ qf32b,
                                              const float* __restrict__ memk,
                                              const float* __restrict__ memv,
                                              float* __restrict__ mout) {
  __shared__ ushort marr[256];
  __shared__ ushort chun[256];
  __shared__ float qf[128];
  __shared__ uint cidx[384];
  __shared__ float csc[384];
  __shared__ unsigned long long ckey[384];
  __shared__ uint selIdx[32];
  __shared__ float selS[32];
  __shared__ float obuf[256];
  __shared__ int nF, nC;
  __shared__ uint sT;

  int i = blockIdx.x;
  const ushort* Srow = Sall + (size_t)i * 16384;
  int t = threadIdx.x;
  int wv = t >> 6, lane = t & 63;
  if (t < 128) qf[t] = qf32b[(size_t)i * 128 + t];
  if (t == 0) { nF = 0; nC = 0; }
  uint cm = cmaxA[(size_t)i * 256 + t];
  marr[t] = (ushort)cm;
  __syncthreads();

  // T' = chunk max with rank 63 (value desc, index asc)
  {
    int rank = 0;
#pragma unroll 8
    for (int j = 0; j < 256; ++j) {
      uint vj = marr[j];
      rank += (vj > cm) || (vj == cm && j < t);
    }
    if (rank == 63) sT = cm;
  }
  __syncthreads();
  uint T = sT;
  if (cm >= T) { int p = atomicAdd(&nF, 1); chun[p] = (ushort)t; }
  __syncthreads();
  int F = nF;

  // scan flagged chunks: 8 threads per chunk, 8 keys per thread
  for (int jj = (t >> 3); jj < F; jj += 32) {
    int base = ((int)chun[jj]) * 64 + (t & 7) * 8;
    uint4 rv = *(const uint4*)(Srow + base);
    uint a0 = ord2(rv.x), a1 = ord2(rv.y), a2 = ord2(rv.z), a3 = ord2(rv.w);
    if ((a0 & 0xffffu) >= T) { int p = atomicAdd(&nC, 1); if (p < 384) cidx[p] = (uint)(base + 0); }
    if ((a0 >> 16)     >= T) { int p = atomicAdd(&nC, 1); if (p < 384) cidx[p] = (uint)(base + 1); }
    if ((a1 & 0xffffu) >= T) { int p = atomicAdd(&nC, 1); if (p < 384) cidx[p] = (uint)(base + 2); }
    if ((a1 >> 16)     >= T) { int p = atomicAdd(&nC, 1); if (p < 384) cidx[p] = (uint)(base + 3); }
    if ((a2 & 0xffffu) >= T) { int p = atomicAdd(&nC, 1); if (p < 384) cidx[p] = (uint)(base + 4); }
    if ((a2 >> 16)     >= T) { int p = atomicAdd(&nC, 1); if (p < 384) cidx[p] = (uint)(base + 5); }
    if ((a3 & 0xffffu) >= T) { int p = atomicAdd(&nC, 1); if (p < 384) cidx[p] = (uint)(base + 6); }
    if ((a3 >> 16)     >= T) { int p = atomicAdd(&nC, 1); if (p < 384) cidx[p] = (uint)(base + 7); }
  }
  __syncthreads();
  int C = nC; if (C > 384) C = 384;

  // refine: exact fp32 scores, 8 candidates in flight per wave (round-7)
  {
    float qa = qf[lane * 2], qb = qf[lane * 2 + 1];
    for (int j0 = wv; j0 < C; j0 += 32) {
      float2 pp[8];
      float s[8];
#pragma unroll
      for (int u = 0; u < 8; ++u) {
        int j = j0 + u * 4;
        if (j < C) pp[u] = *(const float2*)(memk + (size_t)cidx[j] * 128 + lane * 2);
      }
#pragma unroll
      for (int u = 0; u < 8; ++u) {
        int j = j0 + u * 4;
        s[u] = (j < C) ? (qa * pp[u].x + qb * pp[u].y) : 0.f;
      }
#pragma unroll
      for (int off = 32; off; off >>= 1) {
#pragma unroll
        for (int u = 0; u < 8; ++u) s[u] += __shfl_xor(s[u], off);
      }
      if (lane == 0) {
#pragma unroll
        for (int u = 0; u < 8; ++u) {
          int j = j0 + u * 4;
          if (j < C) csc[j] = s[u];
        }
      }
    }
  }
  __syncthreads();
  // rank-by-counting top-32 (comparator: score desc, index asc)
  for (int j = t; j < C; j += 256) {
    uint sb2 = __float_as_uint(csc[j]);
    uint o = (sb2 & 0x80000000u) ? ~sb2 : (sb2 | 0x80000000u);
    ckey[j] = ((unsigned long long)o << 32) | (uint)(~cidx[j]);
  }
  __syncthreads();
  for (int j = t; j < C; j += 256) {
    unsigned long long my = ckey[j];
    int rank = 0;
    for (int l = 0; l < C; ++l) rank += (ckey[l] > my) ? 1 : 0;
    if (rank < 32) { selS[rank] = csc[j]; selIdx[rank] = cidx[j]; }
  }
  __syncthreads();
  // softmax over the 32 (wave 0, identical math)
  if (wv == 0) {
    float sc = (lane < 32) ? selS[lane] * 0.03125f : -1e30f;  // 1/sqrt(1024)
    float mx = sc;
#pragma unroll
    for (int off = 32; off; off >>= 1) mx = fmaxf(mx, __shfl_xor(mx, off));
    float ex = (lane < 32) ? __expf(sc - mx) : 0.f;
    float Z = ex;
#pragma unroll
    for (int off = 32; off; off >>= 1) Z += __shfl_xor(Z, off);
    if (lane < 32) selS[lane] = ex / Z;
  }
  __syncthreads();
  // gather: 256 threads, two j-halves per output element; loads hoisted
  {
    int d = t & 127, half = t >> 7;
    float vv[16];
#pragma unroll
    for (int u = 0; u < 16; ++u)
      vv[u] = memv[(size_t)selIdx[half * 16 + u] * 128 + d];
    float acc = 0.f;
#pragma unroll
    for (int u = 0; u < 16; ++u)
      acc += selS[half * 16 + u] * vv[u];
    obuf[t] = acc;
  }
  __syncthreads();
  if (t < 128) mout[(size_t)i * 128 + t] = obuf[t] + obuf[t + 128];
}

// ---- final gate mix (fp32 out) ----
__global__ __launch_bounds__(256) void k_mix(const float* __restrict__ a,
                                             const float* __restrict__ b,
                                             const float* __restrict__ gate,
                                             float* __restrict__ out) {
  int id = blockIdx.x * 256 + threadIdx.x;   // 262144 chunks of 4
  float g = gate[0];
  float4 va = ((const float4*)a)[id];
  float4 vb = ((const float4*)b)[id];
  float4 o;
  o.x = va.x * g + vb.x * (1.f - g);
  o.y = va.y * g + vb.y * (1.f - g);
  o.z = va.z * g + vb.z * (1.f - g);
  o.w = va.w * g + vb.w * (1.f - g);
  ((float4*)out)[id] = o;
}

extern "C" void kernel_launch(void* const* d_in, const int* in_sizes, int n_in,
                              void* d_out, int out_size, void* d_ws, size_t ws_size,
                              hipStream_t stream) {
  const float* x    = (const float*)d_in[0];
  const float* ki   = (const float*)d_in[1];
  const float* vi   = (const float*)d_in[2];
  const float* mk   = (const float*)d_in[3];
  const float* mv   = (const float*)d_in[4];
  const float* Wq   = (const float*)d_in[5];
  const float* bq   = (const float*)d_in[6];
  const float* Wk   = (const float*)d_in[7];
  const float* bk   = (const float*)d_in[8];
  const float* Wv   = (const float*)d_in[9];
  const float* bv   = (const float*)d_in[10];
  const float* gate = (const float*)d_in[11];
  const int*   idx  = (const int*)d_in[12];

  char* ws = (char*)d_ws;
  ushort* Sbuf  = (ushort*)(ws);                 // 64 MiB scores (SDPA, then per-batch mem)
  ushort* xh    = (ushort*)(ws);                 // 16 MiB bf16 x hi (pre-SDPA only, inside Sbuf)
  ushort* xl    = (ushort*)(ws + 16777216);      // 16 MiB bf16 x lo (pre-SDPA only)
  float*  qex   = (float*) (ws + 67108864);      // 4 MiB fp32 q (near-exact)
  ushort* kfull = (ushort*)(ws + 71303168);      // 4 MiB
  ushort* vfull = (ushort*)(ws + 75497472);      // 4 MiB
  ushort* Vt    = (ushort*)(ws + 79691776);      // 4 MiB
  ushort* mkb   = (ushort*)(ws + 83886080);      // 16 MiB bf16 mem_keys
  ushort* Wth   = (ushort*)(ws + 100663296);     // 768 KiB
  ushort* Wtlq  = (ushort*)(ws + 101449728);     // 256 KiB
  float*  osdpa = (float*) (ws + 101711872);     // 4 MiB
  float*  mout  = (float*) (ws + 105906176);     // 4 MiB
  ushort* cmaxb = (ushort*)(ws + 110100480);     // 1 MiB chunk-max sidecar

  k_wt<<<2048, 256, 0, stream>>>(Wq, Wk, Wv, Wth, Wtlq);
  k_cvt8<<<4096, 256, 0, stream>>>(mk, mkb);     // 4*16384*128 / 8 / 256
  k_xsplit<<<4096, 256, 0, stream>>>(x, xh, xl); // 8192*1024 / 8 / 256
  k_prefix<<<512, 256, 0, stream>>>(ki, vi, idx, kfull, vfull);

  // QKV: 4-wave LDS-pipelined blocks, 128 m-tiles x 2 col-halves x 3 z
  k_qkv3<<<dim3(128, 2, 3), 256, 0, stream>>>(xh, xl, Wth, Wtlq, bq, bk, bv,
                                              qex, kfull, vfull);
  k_vt<<<256, 256, 0, stream>>>(vfull, Vt);

  // SDPA: scores -> windowed softmax (in place) -> PV
  k_scores<<<dim3(32, 8, 4), 256, 0, stream>>>(qex, kfull, Sbuf, nullptr,
                                               4096, 512, 2048,
                                               (long)2048 * 128, (long)4096 * 128,
                                               (long)2048 * 4096);
  k_softmax<<<8192, 256, 0, stream>>>(Sbuf);
  k_pv<<<dim3(64, 4, 4), 128, 0, stream>>>(Sbuf, Vt, osdpa);

  // kNN memory attention, per batch (reuses Sbuf; cmax sidecar per batch)
  for (int b = 0; b < 4; ++b) {
    k_scores<<<dim3(32, 32, 1), 256, 0, stream>>>(qex + (size_t)b * 2048 * 128,
                                                  mkb + (size_t)b * 16384 * 128,
                                                  Sbuf, cmaxb,
                                                  16384, 512, (1 << 28),
                                                  0, 0, 0);
    k_topk<<<2048, 256, 0, stream>>>(Sbuf, cmaxb,
                                     qex + (size_t)b * 2048 * 128,
                                     mk + (size_t)b * 16384 * 128,
                                     mv + (size_t)b * 16384 * 128,
                                     mout + (size_t)b * 2048 * 128);
  }

  k_mix<<<1024, 256, 0, stream>>>(osdpa, mout, gate, (float*)d_out);
}

// Round 14
// 592.649 us; speedup vs baseline: 1.0372x; 1.0215x over previous
//
#include <hip/hip_runtime.h>

// Problem: B=4, Tq=2048, Tk=4096, E=1024, D=128, M=16384, top_k=32
// All inputs/outputs are float32 (reference is pure jnp.float32).
// NOTE: qex bits are load-bearing for the top-k boundary (round-4 post-mortem).
// Round 8: k_qkv3 4-wave LDS 2-phase pipeline. Round 15: chunk-max sidecar for
// k_topk (WIN 746->611). Round 17: k_scores gl16 swizzled staging (WIN ->605).
// Round 18: k_pv — round-7's unverified d-split (49.5 -> 61.4 µs regression,
// exposed by round-12's TLP-invariance: occupancy up, time flat => per-step
// barrier vmcnt(0) drain is the cost) reverted to 32q x 64d AND BK 64->128:
// half the barrier drains for the same bytes. Per-acc k-order still globally
// ascending (st*128 + kc*32) -> osdpa bit-identical.

using bf16x8 = __attribute__((ext_vector_type(8))) short;
using f32x4  = __attribute__((ext_vector_type(4))) float;

typedef __attribute__((address_space(1))) const void GVoid;
typedef __attribute__((address_space(3))) void LVoid;
__device__ __forceinline__ void gl16(const ushort* g, ushort* l) {
  __builtin_amdgcn_global_load_lds((GVoid*)g, (LVoid*)l, 16, 0, 0);
}

__device__ __forceinline__ float bf2f(ushort h) {
  union { uint u; float f; } x; x.u = ((uint)h) << 16; return x.f;
}
__device__ __forceinline__ ushort f2bf(float f) {
  union { float f; uint u; } x; x.f = f;
  uint u = x.u;
  u += 0x7fffu + ((u >> 16) & 1u);   // RNE (finite inputs only)
  return (ushort)(u >> 16);
}
// two bf16 halves (packed in a uint) -> order-preserving uint16 keys.
__device__ __forceinline__ uint ord2(uint v) {
  uint s = (v >> 15) & 0x00010001u;   // per-half sign bit
  uint t = (s << 15) - s;             // 0x7FFF where sign, else 0
  return v ^ t ^ 0x80008000u;
}
// single bf16 -> order-preserving u16 key (same map as ord2 halves)
__device__ __forceinline__ ushort ord1(ushort h) {
  uint s = (h >> 15) & 1u;
  return (ushort)(h ^ ((s << 15) - s) ^ 0x8000u);
}

// ---- Wth[z][n][k] = bf16(W_z[k][n]) for z=0..2; Wtlq[n][k] = lo(Wq[k][n]) ----
__global__ __launch_bounds__(256) void k_wt(const float* __restrict__ Wq,
                                            const float* __restrict__ Wk,
                                            const float* __restrict__ Wv,
                                            ushort* __restrict__ Wth,
                                            ushort* __restrict__ Wtlq) {
  int id = blockIdx.x * 256 + threadIdx.x;        // 4*131072 = 524288 exact
  int z = id >> 17, r = id & 131071;
  int n = r >> 10, k = r & 1023;
  const float* W = (z == 1) ? Wk : (z == 2) ? Wv : Wq;
  float w = W[k * 128 + n];
  ushort h = f2bf(w);
  if (z < 3) Wth[id] = h;
  else       Wtlq[r] = f2bf(w - bf2f(h));
}

// ---- fp32 -> bf16 bulk convert (8 elems/thread) ----
__global__ __launch_bounds__(256) void k_cvt8(const float* __restrict__ src,
                                              ushort* __restrict__ dst) {
  int id = blockIdx.x * 256 + threadIdx.x;
  size_t base = (size_t)id * 8;
  float4 a = *(const float4*)(src + base);
  float4 b = *(const float4*)(src + base + 4);
  bf16x8 r;
  r[0] = (short)f2bf(a.x); r[1] = (short)f2bf(a.y);
  r[2] = (short)f2bf(a.z); r[3] = (short)f2bf(a.w);
  r[4] = (short)f2bf(b.x); r[5] = (short)f2bf(b.y);
  r[6] = (short)f2bf(b.z); r[7] = (short)f2bf(b.w);
  *(bf16x8*)(dst + base) = r;
}

// ---- x -> xh (hi bf16), xl (lo bf16); bit-identical to round-3 ----
__global__ __launch_bounds__(256) void k_xsplit(const float* __restrict__ x,
                                                ushort* __restrict__ xh,
                                                ushort* __restrict__ xl) {
  int id = blockIdx.x * 256 + threadIdx.x;       // 4096*256 threads, 8 elems each
  size_t base = (size_t)id * 8;
  float4 a = *(const float4*)(x + base);
  float4 b = *(const float4*)(x + base + 4);
  float xf[8] = {a.x, a.y, a.z, a.w, b.x, b.y, b.z, b.w};
  bf16x8 rh, rl;
#pragma unroll
  for (int j = 0; j < 8; ++j) {
    ushort h = f2bf(xf[j]);
    rh[j] = (short)h;
    rl[j] = (short)f2bf(xf[j] - bf2f(h));
  }
  *(bf16x8*)(xh + base) = rh;
  *(bf16x8*)(xl + base) = rl;
}

// ---- prefix: k_full/v_full[b][t<2048][d] = bf16(ki/vi[b][t][idx*128+d]) ----
__global__ __launch_bounds__(256) void k_prefix(const float* __restrict__ ki,
                                                const float* __restrict__ vi,
                                                const int* __restrict__ idx,
                                                ushort* __restrict__ kfull,
                                                ushort* __restrict__ vfull) {
  int s = idx[0] * 128;
  int id = blockIdx.x * 256 + threadIdx.x;        // 131072 chunks of 8
  int d8 = (id & 15) * 8;
  int bt = id >> 4;                                // b*2048+t
  int b = bt >> 11, t = bt & 2047;
  const float* kp = ki + (size_t)bt * 1024 + s + d8;
  const float* vp = vi + (size_t)bt * 1024 + s + d8;
  bf16x8 rk, rv;
#pragma unroll
  for (int j = 0; j < 8; ++j) { rk[j] = (short)f2bf(kp[j]); rv[j] = (short)f2bf(vp[j]); }
  size_t dst = ((size_t)b * 4096 + t) * 128 + d8;
  *(bf16x8*)(kfull + dst) = rk;
  *(bf16x8*)(vfull + dst) = rv;
}

// ---- QKV projection, 4-wave LDS 2-phase pipeline (round 8, bit-identical) ----
__global__ __launch_bounds__(256) void k_qkv3(const ushort* __restrict__ xh,
                                              const ushort* __restrict__ xl,
                                              const ushort* __restrict__ Wth,
                                              const ushort* __restrict__ Wtlq,
                                              const float* __restrict__ bq,
                                              const float* __restrict__ bk,
                                              const float* __restrict__ bv,
                                              float* __restrict__ qex,
                                              ushort* __restrict__ kfull,
                                              ushort* __restrict__ vfull) {
  __shared__ ushort lds[2][16384];   // [buf][xh 4096 | xl 4096 | Wh 4096 | Wl 4096]
  int z = blockIdx.z;
  int g = blockIdx.y;                 // column half: n in [g*64, g*64+64)
  int m0 = blockIdx.x * 64;           // 128 tiles of 64 rows
  int tid = threadIdx.x;
  int w = tid >> 6, lane = tid & 63;
  int l15 = lane & 15, q8 = (lane >> 4) * 8;
  const ushort* Wz = Wth + (size_t)z * 131072;
  const ushort* xh_src = xh + (size_t)(m0 + w * 16 + l15) * 1024 + q8;
  const ushort* xl_src = xl + (size_t)(m0 + w * 16 + l15) * 1024 + q8;
  const ushort* wh_src = Wz   + (size_t)(g * 64 + w * 16 + l15) * 1024 + q8;
  const ushort* wl_src = Wtlq + (size_t)(g * 64 + w * 16 + l15) * 1024 + q8;
  int sb = w * 1024;

  f32x4 zero = {0.f, 0.f, 0.f, 0.f};
  f32x4 acc[4] = {zero, zero, zero, zero};

  {
    ushort* B = &lds[0][0];
    gl16(xh_src,      B + sb);
    gl16(xh_src + 32, B + sb + 512);
    gl16(wh_src,      B + 8192 + sb);
    gl16(wh_src + 32, B + 8192 + sb + 512);
    if (z == 0) {
      gl16(xl_src,      B + 4096 + sb);
      gl16(xl_src + 32, B + 4096 + sb + 512);
      gl16(wl_src,      B + 12288 + sb);
      gl16(wl_src + 32, B + 12288 + sb + 512);
    }
  }
  __syncthreads();
  int bf = 0;
  for (int t16 = 0; t16 < 16; ++t16) {
    if (t16 < 15) {
      int k0 = t16 * 64 + 64;
      ushort* B = &lds[bf ^ 1][0];
      gl16(xh_src + k0,      B + sb);
      gl16(xh_src + k0 + 32, B + sb + 512);
      gl16(wh_src + k0,      B + 8192 + sb);
      gl16(wh_src + k0 + 32, B + 8192 + sb + 512);
      if (z == 0) {
        gl16(xl_src + k0,      B + 4096 + sb);
        gl16(xl_src + k0 + 32, B + 4096 + sb + 512);
        gl16(wl_src + k0,      B + 12288 + sb);
        gl16(wl_src + k0 + 32, B + 12288 + sb + 512);
      }
    }
    const ushort* B = &lds[bf][0];
    int lo = lane * 8;
    if (z == 0) {
#pragma unroll
      for (int kc = 0; kc < 2; ++kc) {
        bf16x8 ah = *(const bf16x8*)(B + (w * 2 + kc) * 512 + lo);
        bf16x8 al = *(const bf16x8*)(B + 4096 + (w * 2 + kc) * 512 + lo);
#pragma unroll
        for (int cc = 0; cc < 4; ++cc) {
          bf16x8 bh = *(const bf16x8*)(B + 8192 + (cc * 2 + kc) * 512 + lo);
          bf16x8 bl = *(const bf16x8*)(B + 12288 + (cc * 2 + kc) * 512 + lo);
          acc[cc] = __builtin_amdgcn_mfma_f32_16x16x32_bf16(ah, bh, acc[cc], 0, 0, 0);
          acc[cc] = __builtin_amdgcn_mfma_f32_16x16x32_bf16(ah, bl, acc[cc], 0, 0, 0);
          acc[cc] = __builtin_amdgcn_mfma_f32_16x16x32_bf16(al, bh, acc[cc], 0, 0, 0);
        }
      }
    } else {
#pragma unroll
      for (int kc = 0; kc < 2; ++kc) {
        bf16x8 ah = *(const bf16x8*)(B + (w * 2 + kc) * 512 + lo);
#pragma unroll
        for (int cc = 0; cc < 4; ++cc) {
          bf16x8 bh = *(const bf16x8*)(B + 8192 + (cc * 2 + kc) * 512 + lo);
          acc[cc] = __builtin_amdgcn_mfma_f32_16x16x32_bf16(ah, bh, acc[cc], 0, 0, 0);
        }
      }
    }
    __syncthreads();
    bf ^= 1;
  }

  const float* bias = (z == 0) ? bq : (z == 1) ? bk : bv;
  int mrow = m0 + w * 16 + (lane >> 4) * 4;
#pragma unroll
  for (int cc = 0; cc < 4; ++cc) {
    int n = g * 64 + cc * 16 + l15;
    float bb = bias[n];
#pragma unroll
    for (int r = 0; r < 4; ++r) {
      int m = mrow + r;
      float val = acc[cc][r] + bb;
      if (z == 0) {
        qex[(size_t)m * 128 + n] = val;
      } else {
        int b2 = m >> 11, tt = m & 2047;
        size_t o = ((size_t)b2 * 4096 + 2048 + tt) * 128 + n;
        if (z == 1) kfull[o] = f2bf(val); else vfull[o] = f2bf(val);
      }
    }
  }
}

// ---- Vt[b][d][t] = v_full[b][t][d]  (tiled transpose, bf16) ----
__global__ __launch_bounds__(256) void k_vt(const ushort* __restrict__ vfull,
                                            ushort* __restrict__ Vt) {
  __shared__ ushort lds[64][136];
  int blk = blockIdx.x;                 // 4*64 = 256
  int b = blk >> 6, t0 = (blk & 63) * 64;
  int t = threadIdx.x;
#pragma unroll
  for (int p = 0; p < 4; ++p) {
    int ch = p * 256 + t;               // 1024 chunks of 8 elems
    int row = ch >> 4, c8 = (ch & 15) * 8;
    uint4 v = *(const uint4*)(vfull + ((size_t)b * 4096 + t0 + row) * 128 + c8);
    *(uint4*)(&lds[row][c8]) = v;
  }
  __syncthreads();
#pragma unroll
  for (int p = 0; p < 8; ++p) {
    int q = p * 256 + t;                // 2048 chunks of 4 elems
    int d = q >> 4, t4 = (q & 15) * 4;
    ushort4 o;
    o.x = lds[t4 + 0][d]; o.y = lds[t4 + 1][d];
    o.z = lds[t4 + 2][d]; o.w = lds[t4 + 3][d];
    *(ushort4*)(Vt + ((size_t)b * 128 + d) * 4096 + t0 + t4) = o;
  }
}

// ---- scores GEMM: S[q][n] = bf16(A_f32[q][:]) . Bm_bf16[n][:]  (A.B^T) ----
// Round 17: B staged via gl16 into linear [64][128] LDS, double-buffered,
// swizzled source/read (rule #21). S bit-identical. cmax sidecar (round 15).
__global__ __launch_bounds__(256) void k_scores(const float* __restrict__ A,
                                                const ushort* __restrict__ Bm,
                                                ushort* __restrict__ S,
                                                ushort* __restrict__ cmax,
                                                int N, int nslice, int causalOff,
                                                long sA, long sB, long sS) {
  __shared__ __align__(16) ushort Bt[2][8192];   // 2 x 16KB, [64 rows][128]
  int q0 = blockIdx.x * 64;
  int ns0 = blockIdx.y * nslice;
  int nend = ns0 + nslice; if (nend > N) nend = N;
  int climit = q0 + 64 + causalOff; if (nend > climit) nend = climit;
  if (ns0 >= nend) return;
  int zb = blockIdx.z;
  const float*  Ab = A  + (size_t)zb * sA;
  const ushort* Bb = Bm + (size_t)zb * sB;
  ushort* Sb = S + (size_t)zb * sS;
  int t = threadIdx.x, lane = t & 63, wv = t >> 6;
  int l15 = lane & 15, q8 = (lane >> 4) * 8;
  const float* Arow = Ab + (size_t)(q0 + wv * 16 + l15) * 128 + q8;
  bf16x8 af[4];
#pragma unroll
  for (int kc = 0; kc < 4; ++kc)
#pragma unroll
    for (int j = 0; j < 8; ++j) af[kc][j] = (short)f2bf(Arow[kc * 32 + j]);
  // per-lane staging geometry (stage #i handles rows wv*16+i*4 .. +3)
  int srow[4], soff[4];
#pragma unroll
  for (int i = 0; i < 4; ++i) {
    int br = wv * 16 + i * 4;
    int rr = br + (lane >> 4);
    int c  = (l15) ^ (rr & 7);
    srow[i] = rr;
    soff[i] = c * 8;
  }
  // prologue: stage first tile into buffer 0
  {
#pragma unroll
    for (int i = 0; i < 4; ++i)
      gl16(Bb + (size_t)(ns0 + srow[i]) * 128 + soff[i],
           &Bt[0][(wv * 16 + i * 4) * 128]);
  }
  __syncthreads();
  int bf = 0;
  for (int n0 = ns0; n0 < nend; n0 += 64) {
    if (n0 + 64 < nend) {              // issue next tile's async stage first
#pragma unroll
      for (int i = 0; i < 4; ++i)
        gl16(Bb + (size_t)(n0 + 64 + srow[i]) * 128 + soff[i],
             &Bt[bf ^ 1][(wv * 16 + i * 4) * 128]);
    }
    const ushort* B = &Bt[bf][0];
    f32x4 zero = {0.f, 0.f, 0.f, 0.f};
    f32x4 acc[4] = {zero, zero, zero, zero};
#pragma unroll
    for (int h = 0; h < 4; ++h) {
#pragma unroll
      for (int kc = 0; kc < 4; ++kc) {
        int row = h * 16 + l15;
        int p = (kc * 4 + (lane >> 4)) ^ (row & 7);
        bf16x8 bfr = *(const bf16x8*)(B + row * 128 + p * 8);
        acc[h] = __builtin_amdgcn_mfma_f32_16x16x32_bf16(af[kc], bfr, acc[h], 0, 0, 0);
      }
    }
    int qq = q0 + wv * 16 + (lane >> 4) * 4;
#pragma unroll
    for (int h = 0; h < 4; ++h)
#pragma unroll
      for (int r = 0; r < 4; ++r)
        Sb[(size_t)(qq + r) * N + (n0 + h * 16 + l15)] = f2bf(acc[h][r]);
    if (cmax) {
#pragma unroll
      for (int r = 0; r < 4; ++r) {
        float m = fmaxf(fmaxf(acc[0][r], acc[1][r]), fmaxf(acc[2][r], acc[3][r]));
#pragma unroll
        for (int off = 1; off < 16; off <<= 1) m = fmaxf(m, __shfl_xor(m, off));
        if (l15 == 0)
          cmax[(size_t)(qq + r) * 256 + (n0 >> 6)] = ord1(f2bf(m));
      }
    }
    __syncthreads();                   // drains stage vmcnt + protects buf reuse
    bf ^= 1;
  }
}

// ---- windowed softmax in place: P = softmax(S/sqrt(128)), zeros beyond window ----
__global__ __launch_bounds__(256) void k_softmax(ushort* __restrict__ S) {
  int rid = blockIdx.x;                // 0..8191 (b*2048+i)
  int i = rid & 2047;
  ushort* row = S + (size_t)rid * 4096;
  int w = i + 2049;                    // keys j <= i + 2048
  int t = threadIdx.x;
  const float scale = 0.08838834764831845f;  // 1/sqrt(128)
  float v[16];
  float mx = -1e30f;
#pragma unroll
  for (int c = 0; c < 16; ++c) {
    int e = c * 256 + t;
    float f = -1e30f;
    if (e < w) f = bf2f(row[e]) * scale;
    v[c] = f;
    mx = fmaxf(mx, f);
  }
  __shared__ float red[4];
#pragma unroll
  for (int off = 32; off; off >>= 1) mx = fmaxf(mx, __shfl_xor(mx, off));
  if ((t & 63) == 0) red[t >> 6] = mx;
  __syncthreads();
  mx = fmaxf(fmaxf(red[0], red[1]), fmaxf(red[2], red[3]));
  __syncthreads();
  float ex[16];
  float sum = 0.f;
#pragma unroll
  for (int c = 0; c < 16; ++c) {
    int e = c * 256 + t;
    ex[c] = (e < w) ? __expf(v[c] - mx) : 0.f;
    sum += ex[c];
  }
#pragma unroll
  for (int off = 32; off; off >>= 1) sum += __shfl_xor(sum, off);
  if ((t & 63) == 0) red[t >> 6] = sum;
  __syncthreads();
  sum = red[0] + red[1] + red[2] + red[3];
  float inv = 1.f / sum;
#pragma unroll
  for (int c = 0; c < 16; ++c) {
    int e = c * 256 + t;
    row[e] = f2bf(ex[c] * inv);        // exact zeros beyond window
  }
}

// ---- PV: 32q x 64d per block, 2 waves, BK=128 LDS 2-phase pipeline ----
// Round 18: half the barrier drains of the BK=64 form (same bytes moved).
// Per-acc MFMA k-order globally ascending (st*128 + kc*32) -> bit-identical.
// P beyond the causal window is exact 0 (softmax zeroes the full row).
__global__ __launch_bounds__(128) void k_pv(const ushort* __restrict__ P,
                                            const ushort* __restrict__ Vt,
                                            float* __restrict__ O) {
  __shared__ ushort lds[2][12288];     // [buf][P 4096 | V 8192] ushorts (48 KB)
  int b = blockIdx.z;
  int d0 = blockIdx.y * 64;
  int q0 = blockIdx.x * 32;
  int t = threadIdx.x, lane = t & 63, w = t >> 6;
  int l15 = lane & 15, q8 = (lane >> 4) * 8;
  const ushort* Pq = P + ((size_t)b * 2048 + q0) * 4096;
  const ushort* Vb = Vt + (size_t)b * 128 * 4096;
  const ushort* p_src  = Pq + (size_t)(w * 16 + l15) * 4096 + q8;
  const ushort* v_src0 = Vb + (size_t)(d0 + (w * 2 + 0) * 16 + l15) * 4096 + q8;
  const ushort* v_src1 = Vb + (size_t)(d0 + (w * 2 + 1) * 16 + l15) * 4096 + q8;
  int kend = q0 + 32 + 2048; if (kend > 4096) kend = 4096;
  int ksteps = (kend + 127) >> 7;

  f32x4 zero = {0.f, 0.f, 0.f, 0.f};
  f32x4 acc[4] = {zero, zero, zero, zero};

  // prologue: stage k-step 0 into buffer 0
  {
    ushort* B = &lds[0][0];
#pragma unroll
    for (int kc = 0; kc < 4; ++kc) {
      gl16(p_src + kc * 32,  B + (w * 4 + kc) * 512);
      gl16(v_src0 + kc * 32, B + 4096 + ((w * 2 + 0) * 4 + kc) * 512);
      gl16(v_src1 + kc * 32, B + 4096 + ((w * 2 + 1) * 4 + kc) * 512);
    }
  }
  __syncthreads();
  int bf = 0;
  for (int st = 0; st < ksteps; ++st) {
    if (st + 1 < ksteps) {             // issue next-tile async loads first
      int k0 = st * 128 + 128;
      ushort* B = &lds[bf ^ 1][0];
#pragma unroll
      for (int kc = 0; kc < 4; ++kc) {
        gl16(p_src + k0 + kc * 32,  B + (w * 4 + kc) * 512);
        gl16(v_src0 + k0 + kc * 32, B + 4096 + ((w * 2 + 0) * 4 + kc) * 512);
        gl16(v_src1 + k0 + kc * 32, B + 4096 + ((w * 2 + 1) * 4 + kc) * 512);
      }
    }
    const ushort* B = &lds[bf][0];
    int lo = lane * 8;
#pragma unroll
    for (int kc = 0; kc < 4; ++kc) {
      bf16x8 af = *(const bf16x8*)(B + (w * 4 + kc) * 512 + lo);
#pragma unroll
      for (int nc = 0; nc < 4; ++nc) {
        bf16x8 bfr = *(const bf16x8*)(B + 4096 + (nc * 4 + kc) * 512 + lo);
        acc[nc] = __builtin_amdgcn_mfma_f32_16x16x32_bf16(af, bfr, acc[nc], 0, 0, 0);
      }
    }
    __syncthreads();                   // drains stage vmcnt + joins waves
    bf ^= 1;
  }

  size_t ob = ((size_t)b * 2048 + q0 + w * 16 + (lane >> 4) * 4) * 128;
#pragma unroll
  for (int nc = 0; nc < 4; ++nc)
#pragma unroll
    for (int r = 0; r < 4; ++r)
      O[ob + (size_t)r * 128 + d0 + nc * 16 + l15] = acc[nc][r];
}

// ---- exact top-32 kNN attention, chunk-max assisted (round 15) ----
__global__ __launch_bounds__(256) void k_topk(const ushort* __restrict__ Sall,
                                              const ushort* __restrict__ cmaxA,
                                              const float* __restrict__ qf32b,
                                              const float* __restrict__ memk,
                                              const float* __restrict__ memv,
                                              float* __restrict__ mout) {
  __shared__ ushort marr[256];
  __shared__ ushort chun[256];
  __shared__ float qf[128];
  __shared__ uint cidx[384];
  __shared__ float csc[384];
  __shared__ unsigned long long ckey[384];
  __shared__ uint selIdx[32];
  __shared__ float selS[32];
  __shared__ float obuf[256];
  __shared__ int nF, nC;
  __shared__ uint sT;

  int i = blockIdx.x;
  const ushort* Srow = Sall + (size_t)i * 16384;
  int t = threadIdx.x;
  int wv = t >> 6, lane = t & 63;
  if (t < 128) qf[t] = qf32b[(size_t)i * 128 + t];
  if (t == 0) { nF = 0; nC = 0; }
  uint cm = cmaxA[(size_t)i * 256 + t];
  marr[t] = (ushort)cm;
  __syncthreads();

  // T' = chunk max with rank 63 (value desc, index asc)
  {
    int rank = 0;
#pragma unroll 8
    for (int j = 0; j < 256; ++j) {
      uint vj = marr[j];
      rank += (vj > cm) || (vj == cm && j < t);
    }
    if (rank == 63) sT = cm;
  }
  __syncthreads();
  uint T = sT;
  if (cm >= T) { int p = atomicAdd(&nF, 1); chun[p] = (ushort)t; }
  __syncthreads();
  int F = nF;

  // scan flagged chunks: 8 threads per chunk, 8 keys per thread
  for (int jj = (t >> 3); jj < F; jj += 32) {
    int base = ((int)chun[jj]) * 64 + (t & 7) * 8;
    uint4 rv = *(const uint4*)(Srow + base);
    uint a0 = ord2(rv.x), a1 = ord2(rv.y), a2 = ord2(rv.z), a3 = ord2(rv.w);
    if ((a0 & 0xffffu) >= T) { int p = atomicAdd(&nC, 1); if (p < 384) cidx[p] = (uint)(base + 0); }
    if ((a0 >> 16)     >= T) { int p = atomicAdd(&nC, 1); if (p < 384) cidx[p] = (uint)(base + 1); }
    if ((a1 & 0xffffu) >= T) { int p = atomicAdd(&nC, 1); if (p < 384) cidx[p] = (uint)(base + 2); }
    if ((a1 >> 16)     >= T) { int p = atomicAdd(&nC, 1); if (p < 384) cidx[p] = (uint)(base + 3); }
    if ((a2 & 0xffffu) >= T) { int p = atomicAdd(&nC, 1); if (p < 384) cidx[p] = (uint)(base + 4); }
    if ((a2 >> 16)     >= T) { int p = atomicAdd(&nC, 1); if (p < 384) cidx[p] = (uint)(base + 5); }
    if ((a3 & 0xffffu) >= T) { int p = atomicAdd(&nC, 1); if (p < 384) cidx[p] = (uint)(base + 6); }
    if ((a3 >> 16)     >= T) { int p = atomicAdd(&nC, 1); if (p < 384) cidx[p] = (uint)(base + 7); }
  }
  __syncthreads();
  int C = nC; if (C > 384) C = 384;

  // refine: exact fp32 scores, 8 candidates in flight per wave (round-7)
  {
    float qa = qf[lane * 2], qb = qf[lane * 2 + 1];
    for (int j0 = wv; j0 < C; j0 += 32) {
      float2 pp[8];
      float s[8];
#pragma unroll
      for (int u = 0; u < 8; ++u) {
        int j = j0 + u * 4;
        if (j < C) pp[u] = *(const float2*)(memk + (size_t)cidx[j] * 128 + lane * 2);
      }
#pragma unroll
      for (int u = 0; u < 8; ++u) {
        int j = j0 + u * 4;
        s[u] = (j < C) ? (qa * pp[u].x + qb * pp[u].y) : 0.f;
      }
#pragma unroll
      for (int off = 32; off; off >>= 1) {
#pragma unroll
        for (int u = 0; u < 8; ++u) s[u] += __shfl_xor(s[u], off);
      }
      if (lane == 0) {
#pragma unroll
        for (int u = 0; u < 8; ++u) {
          int j = j0 + u * 4;
          if (j < C) csc[j] = s[u];
        }
      }
    }
  }
  __syncthreads();
  // rank-by-counting top-32 (comparator: score desc, index asc)
  for (int j = t; j < C; j += 256) {
    uint sb2 = __float_as_uint(csc[j]);
    uint o = (sb2 & 0x80000000u) ? ~sb2 : (sb2 | 0x80000000u);
    ckey[j] = ((unsigned long long)o << 32) | (uint)(~cidx[j]);
  }
  __syncthreads();
  for (int j = t; j < C; j += 256) {
    unsigned long long my = ckey[j];
    int rank = 0;
    for (int l = 0; l < C; ++l) rank += (ckey[l] > my) ? 1 : 0;
    if (rank < 32) { selS[rank] = csc[j]; selIdx[rank] = cidx[j]; }
  }
  __syncthreads();
  // softmax over the 32 (wave 0, identical math)
  if (wv == 0) {
    float sc = (lane < 32) ? selS[lane] * 0.03125f : -1e30f;  // 1/sqrt(1024)
    float mx = sc;
#pragma unroll
    for (int off = 32; off; off >>= 1) mx = fmaxf(mx, __shfl_xor(mx, off));
    float ex = (lane < 32) ? __expf(sc - mx) : 0.f;
    float Z = ex;
#pragma unroll
    for (int off = 32; off; off >>= 1) Z += __shfl_xor(Z, off);
    if (lane < 32) selS[lane] = ex / Z;
  }
  __syncthreads();
  // gather: 256 threads, two j-halves per output element; loads hoisted
  {
    int d = t & 127, half = t >> 7;
    float vv[16];
#pragma unroll
    for (int u = 0; u < 16; ++u)
      vv[u] = memv[(size_t)selIdx[half * 16 + u] * 128 + d];
    float acc = 0.f;
#pragma unroll
    for (int u = 0; u < 16; ++u)
      acc += selS[half * 16 + u] * vv[u];
    obuf[t] = acc;
  }
  __syncthreads();
  if (t < 128) mout[(size_t)i * 128 + t] = obuf[t] + obuf[t + 128];
}

// ---- final gate mix (fp32 out) ----
__global__ __launch_bounds__(256) void k_mix(const float* __restrict__ a,
                                             const float* __restrict__ b,
                                             const float* __restrict__ gate,
                                             float* __restrict__ out) {
  int id = blockIdx.x * 256 + threadIdx.x;   // 262144 chunks of 4
  float g = gate[0];
  float4 va = ((const float4*)a)[id];
  float4 vb = ((const float4*)b)[id];
  float4 o;
  o.x = va.x * g + vb.x * (1.f - g);
  o.y = va.y * g + vb.y * (1.f - g);
  o.z = va.z * g + vb.z * (1.f - g);
  o.w = va.w * g + vb.w * (1.f - g);
  ((float4*)out)[id] = o;
}

extern "C" void kernel_launch(void* const* d_in, const int* in_sizes, int n_in,
                              void* d_out, int out_size, void* d_ws, size_t ws_size,
                              hipStream_t stream) {
  const float* x    = (const float*)d_in[0];
  const float* ki   = (const float*)d_in[1];
  const float* vi   = (const float*)d_in[2];
  const float* mk   = (const float*)d_in[3];
  const float* mv   = (const float*)d_in[4];
  const float* Wq   = (const float*)d_in[5];
  const float* bq   = (const float*)d_in[6];
  const float* Wk   = (const float*)d_in[7];
  const float* bk   = (const float*)d_in[8];
  const float* Wv   = (const float*)d_in[9];
  const float* bv   = (const float*)d_in[10];
  const float* gate = (const float*)d_in[11];
  const int*   idx  = (const int*)d_in[12];

  char* ws = (char*)d_ws;
  ushort* Sbuf  = (ushort*)(ws);                 // 64 MiB scores (SDPA, then per-batch mem)
  ushort* xh    = (ushort*)(ws);                 // 16 MiB bf16 x hi (pre-SDPA only, inside Sbuf)
  ushort* xl    = (ushort*)(ws + 16777216);      // 16 MiB bf16 x lo (pre-SDPA only)
  float*  qex   = (float*) (ws + 67108864);      // 4 MiB fp32 q (near-exact)
  ushort* kfull = (ushort*)(ws + 71303168);      // 4 MiB
  ushort* vfull = (ushort*)(ws + 75497472);      // 4 MiB
  ushort* Vt    = (ushort*)(ws + 79691776);      // 4 MiB
  ushort* mkb   = (ushort*)(ws + 83886080);      // 16 MiB bf16 mem_keys
  ushort* Wth   = (ushort*)(ws + 100663296);     // 768 KiB
  ushort* Wtlq  = (ushort*)(ws + 101449728);     // 256 KiB
  float*  osdpa = (float*) (ws + 101711872);     // 4 MiB
  float*  mout  = (float*) (ws + 105906176);     // 4 MiB
  ushort* cmaxb = (ushort*)(ws + 110100480);     // 1 MiB chunk-max sidecar

  k_wt<<<2048, 256, 0, stream>>>(Wq, Wk, Wv, Wth, Wtlq);
  k_cvt8<<<4096, 256, 0, stream>>>(mk, mkb);     // 4*16384*128 / 8 / 256
  k_xsplit<<<4096, 256, 0, stream>>>(x, xh, xl); // 8192*1024 / 8 / 256
  k_prefix<<<512, 256, 0, stream>>>(ki, vi, idx, kfull, vfull);

  // QKV: 4-wave LDS-pipelined blocks, 128 m-tiles x 2 col-halves x 3 z
  k_qkv3<<<dim3(128, 2, 3), 256, 0, stream>>>(xh, xl, Wth, Wtlq, bq, bk, bv,
                                              qex, kfull, vfull);
  k_vt<<<256, 256, 0, stream>>>(vfull, Vt);

  // SDPA: scores -> windowed softmax (in place) -> PV (BK=128)
  k_scores<<<dim3(32, 8, 4), 256, 0, stream>>>(qex, kfull, Sbuf, nullptr,
                                               4096, 512, 2048,
                                               (long)2048 * 128, (long)4096 * 128,
                                               (long)2048 * 4096);
  k_softmax<<<8192, 256, 0, stream>>>(Sbuf);
  k_pv<<<dim3(64, 2, 4), 128, 0, stream>>>(Sbuf, Vt, osdpa);

  // kNN memory attention, per batch (reuses Sbuf; cmax sidecar per batch)
  for (int b = 0; b < 4; ++b) {
    k_scores<<<dim3(32, 32, 1), 256, 0, stream>>>(qex + (size_t)b * 2048 * 128,
                                                  mkb + (size_t)b * 16384 * 128,
                                                  Sbuf, cmaxb,
                                                  16384, 512, (1 << 28),
                                                  0, 0, 0);
    k_topk<<<2048, 256, 0, stream>>>(Sbuf, cmaxb,
                                     qex + (size_t)b * 2048 * 128,
                                     mk + (size_t)b * 16384 * 128,
                                     mv + (size_t)b * 16384 * 128,
                                     mout + (size_t)b * 2048 * 128);
  }

  k_mix<<<1024, 256, 0, stream>>>(osdpa, mout, gate, (float*)d_out);
}